// Round 17
// baseline (1639.336 us; speedup 1.0000x reference)
//
#include <hip/hip_runtime.h>
#include <math.h>

#define D 128
#define NSTATE 16
#define DR 8
#define T_SEQ 1024
#define NTOK 131072  // 128 sequences * 1024 tokens
#define SEG 8        // segments per sequence (parallel scan)
#define SEGLEN 128   // T_SEQ / SEG
#define ZS 136       // bf16 elems per z row (128 + 8 pad -> 272B stride)
#define XRS2 132     // f32 elems per xr row (128 + 4 pad)

typedef __attribute__((ext_vector_type(8))) short bf16x8;
typedef __attribute__((ext_vector_type(4))) float f32x4;

#define LOG2E 1.44269504088896340736f
#define LN2   0.69314718055994530942f

// fast sigmoid: 1/(1+2^(-x*log2e)) via v_exp + v_rcp (~1 ulp)
__device__ __forceinline__ float sigmoidf_(float x) {
    return __builtin_amdgcn_rcpf(1.0f + exp2f(-x * LOG2E));
}
// fast softplus: ln2 * log2(1 + 2^(x*log2e)) via v_exp + v_log
__device__ __forceinline__ float softplusf_(float x) {
    float t = LN2 * __builtin_amdgcn_logf(1.0f + exp2f(x * LOG2E));
    return (x > 20.0f) ? x : t;
}
__device__ __forceinline__ short f2bf(float f) {   // RNE float->bf16
    union { float f; unsigned u; } v; v.f = f;
    unsigned r = v.u + 0x7FFFu + ((v.u >> 16) & 1u);
    return (short)(r >> 16);
}
__device__ __forceinline__ float bf2f(short s) {
    union { unsigned u; float f; } v; v.u = ((unsigned)(unsigned short)s) << 16;
    return v.f;
}

// ---------------- prep kernels ----------------

// f32 -> bf16 hi/lo split, elementwise (layout preserved)
__global__ void k_prepw(const float* __restrict__ src, short* __restrict__ hi,
                        short* __restrict__ lo, int n) {
    int i = blockIdx.x * 256 + threadIdx.x;
    if (i < n) {
        float f = src[i];
        short hh = f2bf(f);
        hi[i] = hh;
        lo[i] = f2bf(f - bf2f(hh));
    }
}

// xp_w (L,40,128) -> padded (L,48,128) bf16 hi/lo, rows 40..47 zero
__global__ void k_prepw_xp(const float* __restrict__ src, short* __restrict__ hi,
                           short* __restrict__ lo) {
    int i = blockIdx.x * 256 + threadIdx.x;     // over 4*48*128
    if (i >= 4 * 48 * 128) return;
    int l = i / (48 * 128);
    int rem = i - l * 48 * 128;
    int j = rem >> 7, k = rem & 127;
    float f = (j < 40) ? src[(l * 40 + j) * 128 + k] : 0.f;
    short hh = f2bf(f);
    hi[i] = hh;
    lo[i] = f2bf(f - bf2f(hh));
}

// A2 = -exp(A_log) * log2(e)
__global__ void k_a2(const float* __restrict__ A_log, float* __restrict__ A2, int total) {
    int idx = blockIdx.x * blockDim.x + threadIdx.x;
    if (idx < total) A2[idx] = -__expf(A_log[idx]) * LOG2E;
}

// h[tok][d] = x[tok] * inp_w[d] + inp_b[d]
__global__ void k_init_h(const float* __restrict__ x, const float* __restrict__ inp_w,
                         const float* __restrict__ inp_b, float* __restrict__ h) {
    int idx = blockIdx.x * blockDim.x + threadIdx.x;
    int tok = idx >> 7;
    int d = idx & 127;
    h[idx] = x[tok] * inp_w[d] + inp_b[d];
}

// ---------------- per-layer kernels ----------------
// Fused LN + in_proj (3-term split-bf16 MFMA) + causal conv(k=3) + SiLU
// + x_proj (second MFMA stage) -> xc, res, bc, dlt. Coalesced flush via LDS.
__global__ __launch_bounds__(256) void k_ln_inproj_conv(
    const float* __restrict__ h, const float* __restrict__ ln_g, const float* __restrict__ ln_b,
    const short* __restrict__ wh, const short* __restrict__ wl,   // in_proj (256,128) hi/lo
    const short* __restrict__ xph, const short* __restrict__ xpl, // x_proj padded (48,128) hi/lo
    const float* __restrict__ conv_w, const float* __restrict__ conv_b,
    float* __restrict__ xc, float* __restrict__ res,
    float* __restrict__ bc, float* __restrict__ dlt)
{
    __shared__ __align__(16) short zsh[48 * ZS];
    __shared__ __align__(16) short zsl[48 * ZS];
    __shared__ __align__(16) float xr[34 * XRS2];
    __shared__ __align__(16) float dbc_l[32][52];   // stage-2 out (40 used, 52 stride)
    const int tid = threadIdx.x;
    const int wv = tid >> 6, lane = tid & 63;
    const int tstart = blockIdx.x * 32;
    const int tin = tstart & (T_SEQ - 1);

    // Phase A: LayerNorm rows 0..33 -> bf16 hi/lo
    for (int r = wv; r < 34; r += 4) {
        int tr = tin + r - 2;
        if (tr < 0) {
            zsh[r * ZS + lane] = 0; zsh[r * ZS + lane + 64] = 0;
            zsl[r * ZS + lane] = 0; zsl[r * ZS + lane + 64] = 0;
            continue;
        }
        size_t row = (size_t)(tstart + r - 2) * D;
        float a = h[row + lane];
        float b = h[row + lane + 64];
        float s = a + b, ss = a * a + b * b;
        #pragma unroll
        for (int m = 1; m < 64; m <<= 1) { s += __shfl_xor(s, m); ss += __shfl_xor(ss, m); }
        float mu = s * (1.0f / 128.0f);
        float var = ss * (1.0f / 128.0f) - mu * mu;
        float rstd = rsqrtf(var + 1e-5f);
        float z0 = (a - mu) * rstd * ln_g[lane]      + ln_b[lane];
        float z1 = (b - mu) * rstd * ln_g[lane + 64] + ln_b[lane + 64];
        short h0 = f2bf(z0), h1 = f2bf(z1);
        zsh[r * ZS + lane]      = h0;
        zsh[r * ZS + lane + 64] = h1;
        zsl[r * ZS + lane]      = f2bf(z0 - bf2f(h0));
        zsl[r * ZS + lane + 64] = f2bf(z1 - bf2f(h1));
    }
    for (int i = tid; i < 14 * 128; i += 256) {
        int r = 34 + (i >> 7), c = i & 127;
        zsh[r * ZS + c] = 0;
        zsl[r * ZS + c] = 0;
    }

    // B panel (hi) -> registers
    const int colb = wv * 64 + (lane & 15);
    const int kb = (lane >> 4) * 8;
    bf16x8 bw[4][4];
    #pragma unroll
    for (int ct = 0; ct < 4; ++ct)
        #pragma unroll
        for (int kf = 0; kf < 4; ++kf)
            bw[ct][kf] = *(const bf16x8*)&wh[(colb + ct * 16) * 128 + kf * 32 + kb];
    __syncthreads();

    f32x4 acc[3][4];
    #pragma unroll
    for (int b = 0; b < 3; ++b)
        #pragma unroll
        for (int ct = 0; ct < 4; ++ct)
            acc[b][ct] = (f32x4){0.f, 0.f, 0.f, 0.f};

    // Pass 1: (a_hi + a_lo) * b_hi
    #pragma unroll
    for (int b = 0; b < 3; ++b) {
        bf16x8 ah[4], al[4];
        const int rbase = (b * 16 + (lane & 15)) * ZS + kb;
        #pragma unroll
        for (int kf = 0; kf < 4; ++kf) {
            ah[kf] = *(const bf16x8*)&zsh[rbase + kf * 32];
            al[kf] = *(const bf16x8*)&zsl[rbase + kf * 32];
        }
        #pragma unroll
        for (int ct = 0; ct < 4; ++ct)
            #pragma unroll
            for (int kf = 0; kf < 4; ++kf) {
                acc[b][ct] = __builtin_amdgcn_mfma_f32_16x16x32_bf16(ah[kf], bw[ct][kf], acc[b][ct], 0, 0, 0);
                acc[b][ct] = __builtin_amdgcn_mfma_f32_16x16x32_bf16(al[kf], bw[ct][kf], acc[b][ct], 0, 0, 0);
            }
    }
    // Pass 2: a_hi * b_lo
    #pragma unroll
    for (int ct = 0; ct < 4; ++ct)
        #pragma unroll
        for (int kf = 0; kf < 4; ++kf)
            bw[ct][kf] = *(const bf16x8*)&wl[(colb + ct * 16) * 128 + kf * 32 + kb];
    #pragma unroll
    for (int b = 0; b < 3; ++b) {
        bf16x8 ah[4];
        const int rbase = (b * 16 + (lane & 15)) * ZS + kb;
        #pragma unroll
        for (int kf = 0; kf < 4; ++kf)
            ah[kf] = *(const bf16x8*)&zsh[rbase + kf * 32];
        #pragma unroll
        for (int ct = 0; ct < 4; ++ct)
            #pragma unroll
            for (int kf = 0; kf < 4; ++kf)
                acc[b][ct] = __builtin_amdgcn_mfma_f32_16x16x32_bf16(ah[kf], bw[ct][kf], acc[b][ct], 0, 0, 0);
    }

    // conv-half acc (waves 0-1) -> xr; gate half stays in registers
    if (wv < 2) {
        #pragma unroll
        for (int b = 0; b < 3; ++b)
            #pragma unroll
            for (int ct = 0; ct < 4; ++ct) {
                const int col = wv * 64 + ct * 16 + (lane & 15);
                #pragma unroll
                for (int i = 0; i < 4; ++i) {
                    int row = b * 16 + ((lane >> 4) << 2) + i;
                    if (row < 34) xr[row * XRS2 + col] = acc[b][ct][i];
                }
            }
    }
    __syncthreads();

    // Epilogue: conv+silu, 256 threads (channel = tid&127, token half = tid>>7)
    {
        int ch = tid & 127, s0 = (tid >> 7) * 16;
        float c0 = conv_w[ch * 3 + 0], c1 = conv_w[ch * 3 + 1], c2 = conv_w[ch * 3 + 2];
        float cb = conv_b[ch];
        float v0 = xr[(s0 + 0) * XRS2 + ch], v1 = xr[(s0 + 1) * XRS2 + ch];
        #pragma unroll
        for (int s = 0; s < 16; ++s) {
            float v2 = xr[(s0 + s + 2) * XRS2 + ch];
            float v = v0 * c0 + v1 * c1 + v2 * c2 + cb;
            v = v * sigmoidf_(v);
            xc[(size_t)(tstart + s0 + s) * D + ch] = v;
            short hh = f2bf(v);
            zsh[(s0 + s) * ZS + ch] = hh;
            zsl[(s0 + s) * ZS + ch] = f2bf(v - bf2f(hh));
            v0 = v1; v1 = v2;
        }
    }
    __syncthreads();

    // gate-half acc (waves 2-3) -> xr rows 2..33 (xr conv columns free now);
    if (wv >= 2) {
        #pragma unroll
        for (int b = 0; b < 3; ++b)
            #pragma unroll
            for (int ct = 0; ct < 4; ++ct) {
                const int col = (wv - 2) * 64 + ct * 16 + (lane & 15);
                #pragma unroll
                for (int i = 0; i < 4; ++i) {
                    int row = b * 16 + ((lane >> 4) << 2) + i;
                    if (row >= 2 && row < 34) xr[row * XRS2 + col] = acc[b][ct][i];
                }
            }
    }
    // Stage 2 MFMA: dbc = xc @ xp_w.T (M=32, N=48 padded, K=128), 3-term split.
    for (int tile = wv; tile < 6; tile += 4) {
        const int b = tile & 1, ct = tile >> 1;
        const int jcol = ct * 16 + (lane & 15);
        const int rbase = (b * 16 + (lane & 15)) * ZS + kb;
        bf16x8 ah[4], al[4], bh[4];
        #pragma unroll
        for (int kf = 0; kf < 4; ++kf) {
            ah[kf] = *(const bf16x8*)&zsh[rbase + kf * 32];
            al[kf] = *(const bf16x8*)&zsl[rbase + kf * 32];
            bh[kf] = *(const bf16x8*)&xph[jcol * 128 + kf * 32 + kb];
        }
        f32x4 a2 = (f32x4){0.f, 0.f, 0.f, 0.f};
        #pragma unroll
        for (int kf = 0; kf < 4; ++kf) {
            a2 = __builtin_amdgcn_mfma_f32_16x16x32_bf16(ah[kf], bh[kf], a2, 0, 0, 0);
            a2 = __builtin_amdgcn_mfma_f32_16x16x32_bf16(al[kf], bh[kf], a2, 0, 0, 0);
        }
        #pragma unroll
        for (int kf = 0; kf < 4; ++kf) {
            bh[kf] = *(const bf16x8*)&xpl[jcol * 128 + kf * 32 + kb];
            a2 = __builtin_amdgcn_mfma_f32_16x16x32_bf16(ah[kf], bh[kf], a2, 0, 0, 0);
        }
        #pragma unroll
        for (int i = 0; i < 4; ++i) {
            int t = b * 16 + ((lane >> 4) << 2) + i;
            dbc_l[t][jcol] = a2[i];
        }
    }
    __syncthreads();

    // Coalesced flush: res (32 x 512B), bc (4KB contig), dlt (1KB contig)
    for (int fi = tid; fi < 1024; fi += 256) {
        int r = fi >> 5, c4 = fi & 31;
        *(float4*)&res[(size_t)(tstart + r) * D + c4 * 4] =
            *(const float4*)&xr[(r + 2) * XRS2 + c4 * 4];
    }
    {
        int t = tid >> 3, q = tid & 7;
        *(float4*)&bc[(size_t)(tstart + t) * 32 + q * 4] = *(const float4*)&dbc_l[t][8 + q * 4];
    }
    if (tid < 64) {
        int t = tid >> 1, j4 = tid & 1;
        *(float4*)&dlt[(size_t)(tstart + t) * 8 + j4 * 4] = *(const float4*)&dbc_l[t][j4 * 4];
    }
}

// ---- LDS-free streaming selective scan: one thread per (segment, d) row ----
// Wave-uniform dlt/bc loads (scalar-cache), per-lane coalesced u loads.
// No __shared__, no barriers. Grid: 512 blocks x 256 thr = 1024 segments.
// Pass 1: scan from x=0 -> F, P(=exp2(A2*sum dt)).
__global__ __launch_bounds__(256) void k_scan1(
    const float* __restrict__ xc, const float* __restrict__ bc,
    const float* __restrict__ dlt,
    const float* __restrict__ dp_w, const float* __restrict__ dp_b,
    const float* __restrict__ A2,
    float* __restrict__ Pbuf, float* __restrict__ Fbuf)
{
    const int tid = threadIdx.x;
    const int d = tid & 127;
    const int segid = blockIdx.x * 2 + (tid >> 7);  // = bt*SEG + seg  (0..1023)
    const size_t segbase = (size_t)segid * SEGLEN;  // token index

    float dpw[DR];
    #pragma unroll
    for (int r = 0; r < DR; ++r) dpw[r] = dp_w[d * DR + r];
    const float dpb = dp_b[d];
    float A2r[NSTATE];
    #pragma unroll
    for (int n = 0; n < NSTATE; ++n) A2r[n] = A2[d * NSTATE + n];
    float xs[NSTATE];
    #pragma unroll
    for (int n = 0; n < NSTATE; ++n) xs[n] = 0.f;
    float S = 0.f;

    // prefetch step 0
    float4 dl0 = *(const float4*)&dlt[segbase * 8];
    float4 dl1 = *(const float4*)&dlt[segbase * 8 + 4];
    float4 B0 = *(const float4*)&bc[segbase * 32 + 0];
    float4 B1 = *(const float4*)&bc[segbase * 32 + 4];
    float4 B2 = *(const float4*)&bc[segbase * 32 + 8];
    float4 B3 = *(const float4*)&bc[segbase * 32 + 12];
    float uv = xc[segbase * D + d];

    for (int tl = 0; tl < SEGLEN; ++tl) {
        float4 cd0 = dl0, cd1 = dl1, cB0 = B0, cB1 = B1, cB2 = B2, cB3 = B3;
        float cu = uv;
        if (tl + 1 < SEGLEN) {
            const size_t nt = segbase + tl + 1;
            dl0 = *(const float4*)&dlt[nt * 8];
            dl1 = *(const float4*)&dlt[nt * 8 + 4];
            B0 = *(const float4*)&bc[nt * 32 + 0];
            B1 = *(const float4*)&bc[nt * 32 + 4];
            B2 = *(const float4*)&bc[nt * 32 + 8];
            B3 = *(const float4*)&bc[nt * 32 + 12];
            uv = xc[nt * D + d];
        }
        float v = dpb;
        v = fmaf(cd0.x, dpw[0], v); v = fmaf(cd0.y, dpw[1], v);
        v = fmaf(cd0.z, dpw[2], v); v = fmaf(cd0.w, dpw[3], v);
        v = fmaf(cd1.x, dpw[4], v); v = fmaf(cd1.y, dpw[5], v);
        v = fmaf(cd1.z, dpw[6], v); v = fmaf(cd1.w, dpw[7], v);
        float dt = softplusf_(v);
        float duv = dt * cu;
        S += dt;
        xs[0]  = fmaf(exp2f(dt * A2r[0]),  xs[0],  duv * cB0.x);
        xs[1]  = fmaf(exp2f(dt * A2r[1]),  xs[1],  duv * cB0.y);
        xs[2]  = fmaf(exp2f(dt * A2r[2]),  xs[2],  duv * cB0.z);
        xs[3]  = fmaf(exp2f(dt * A2r[3]),  xs[3],  duv * cB0.w);
        xs[4]  = fmaf(exp2f(dt * A2r[4]),  xs[4],  duv * cB1.x);
        xs[5]  = fmaf(exp2f(dt * A2r[5]),  xs[5],  duv * cB1.y);
        xs[6]  = fmaf(exp2f(dt * A2r[6]),  xs[6],  duv * cB1.z);
        xs[7]  = fmaf(exp2f(dt * A2r[7]),  xs[7],  duv * cB1.w);
        xs[8]  = fmaf(exp2f(dt * A2r[8]),  xs[8],  duv * cB2.x);
        xs[9]  = fmaf(exp2f(dt * A2r[9]),  xs[9],  duv * cB2.y);
        xs[10] = fmaf(exp2f(dt * A2r[10]), xs[10], duv * cB2.z);
        xs[11] = fmaf(exp2f(dt * A2r[11]), xs[11], duv * cB2.w);
        xs[12] = fmaf(exp2f(dt * A2r[12]), xs[12], duv * cB3.x);
        xs[13] = fmaf(exp2f(dt * A2r[13]), xs[13], duv * cB3.y);
        xs[14] = fmaf(exp2f(dt * A2r[14]), xs[14], duv * cB3.z);
        xs[15] = fmaf(exp2f(dt * A2r[15]), xs[15], duv * cB3.w);
    }
    const size_t o = ((size_t)segid * D + d) * NSTATE;
    #pragma unroll
    for (int nq = 0; nq < 4; ++nq) {
        *(float4*)&Fbuf[o + nq * 4] =
            make_float4(xs[nq*4], xs[nq*4+1], xs[nq*4+2], xs[nq*4+3]);
        *(float4*)&Pbuf[o + nq * 4] =
            make_float4(exp2f(A2r[nq*4] * S), exp2f(A2r[nq*4+1] * S),
                        exp2f(A2r[nq*4+2] * S), exp2f(A2r[nq*4+3] * S));
    }
}

// Pass 2: inline fix-up -> x_init, re-scan; y = C.x + u*Dp, gated, -> resy.
__global__ __launch_bounds__(256) void k_scan2(
    const float* __restrict__ xc, const float* __restrict__ bc,
    const float* __restrict__ dlt,
    const float* __restrict__ dp_w, const float* __restrict__ dp_b,
    const float* __restrict__ A2, const float* __restrict__ Dp,
    const float* __restrict__ Pbuf, const float* __restrict__ Fbuf,
    float* __restrict__ resy)
{
    const int tid = threadIdx.x;
    const int d = tid & 127;
    const int segid = blockIdx.x * 2 + (tid >> 7);  // 0..1023
    const int bt = segid >> 3, seg = segid & 7;
    const size_t segbase = (size_t)segid * SEGLEN;

    float dpw[DR];
    #pragma unroll
    for (int r = 0; r < DR; ++r) dpw[r] = dp_w[d * DR + r];
    const float dpb = dp_b[d];
    float A2r[NSTATE];
    #pragma unroll
    for (int n = 0; n < NSTATE; ++n) A2r[n] = A2[d * NSTATE + n];
    const float Dpd = Dp[d];

    // inline fix-up: x_init = serial combine over segments 0..seg-1
    float xs[NSTATE];
    #pragma unroll
    for (int n = 0; n < NSTATE; ++n) xs[n] = 0.f;
    for (int s = 0; s < seg; ++s) {
        const size_t idx = ((size_t)(bt * SEG + s) * D + d) * NSTATE;
        #pragma unroll
        for (int nq = 0; nq < 4; ++nq) {
            float4 P = *(const float4*)&Pbuf[idx + nq * 4];
            float4 F = *(const float4*)&Fbuf[idx + nq * 4];
            xs[nq*4+0] = fmaf(P.x, xs[nq*4+0], F.x);
            xs[nq*4+1] = fmaf(P.y, xs[nq*4+1], F.y);
            xs[nq*4+2] = fmaf(P.z, xs[nq*4+2], F.z);
            xs[nq*4+3] = fmaf(P.w, xs[nq*4+3], F.w);
        }
    }

    // prefetch step 0
    float4 dl0 = *(const float4*)&dlt[segbase * 8];
    float4 dl1 = *(const float4*)&dlt[segbase * 8 + 4];
    float4 B0 = *(const float4*)&bc[segbase * 32 + 0];
    float4 B1 = *(const float4*)&bc[segbase * 32 + 4];
    float4 B2 = *(const float4*)&bc[segbase * 32 + 8];
    float4 B3 = *(const float4*)&bc[segbase * 32 + 12];
    float4 C0 = *(const float4*)&bc[segbase * 32 + 16];
    float4 C1 = *(const float4*)&bc[segbase * 32 + 20];
    float4 C2 = *(const float4*)&bc[segbase * 32 + 24];
    float4 C3 = *(const float4*)&bc[segbase * 32 + 28];
    float uv = xc[segbase * D + d];
    float rg = resy[segbase * D + d];

    for (int tl = 0; tl < SEGLEN; ++tl) {
        float4 cd0 = dl0, cd1 = dl1;
        float4 cB0 = B0, cB1 = B1, cB2 = B2, cB3 = B3;
        float4 cC0 = C0, cC1 = C1, cC2 = C2, cC3 = C3;
        float cu = uv, cg = rg;
        if (tl + 1 < SEGLEN) {
            const size_t nt = segbase + tl + 1;
            dl0 = *(const float4*)&dlt[nt * 8];
            dl1 = *(const float4*)&dlt[nt * 8 + 4];
            B0 = *(const float4*)&bc[nt * 32 + 0];
            B1 = *(const float4*)&bc[nt * 32 + 4];
            B2 = *(const float4*)&bc[nt * 32 + 8];
            B3 = *(const float4*)&bc[nt * 32 + 12];
            C0 = *(const float4*)&bc[nt * 32 + 16];
            C1 = *(const float4*)&bc[nt * 32 + 20];
            C2 = *(const float4*)&bc[nt * 32 + 24];
            C3 = *(const float4*)&bc[nt * 32 + 28];
            uv = xc[nt * D + d];
            rg = resy[nt * D + d];
        }
        float v = dpb;
        v = fmaf(cd0.x, dpw[0], v); v = fmaf(cd0.y, dpw[1], v);
        v = fmaf(cd0.z, dpw[2], v); v = fmaf(cd0.w, dpw[3], v);
        v = fmaf(cd1.x, dpw[4], v); v = fmaf(cd1.y, dpw[5], v);
        v = fmaf(cd1.z, dpw[6], v); v = fmaf(cd1.w, dpw[7], v);
        float dt = softplusf_(v);
        float duv = dt * cu;
        xs[0]  = fmaf(exp2f(dt * A2r[0]),  xs[0],  duv * cB0.x);
        xs[1]  = fmaf(exp2f(dt * A2r[1]),  xs[1],  duv * cB0.y);
        xs[2]  = fmaf(exp2f(dt * A2r[2]),  xs[2],  duv * cB0.z);
        xs[3]  = fmaf(exp2f(dt * A2r[3]),  xs[3],  duv * cB0.w);
        xs[4]  = fmaf(exp2f(dt * A2r[4]),  xs[4],  duv * cB1.x);
        xs[5]  = fmaf(exp2f(dt * A2r[5]),  xs[5],  duv * cB1.y);
        xs[6]  = fmaf(exp2f(dt * A2r[6]),  xs[6],  duv * cB1.z);
        xs[7]  = fmaf(exp2f(dt * A2r[7]),  xs[7],  duv * cB1.w);
        xs[8]  = fmaf(exp2f(dt * A2r[8]),  xs[8],  duv * cB2.x);
        xs[9]  = fmaf(exp2f(dt * A2r[9]),  xs[9],  duv * cB2.y);
        xs[10] = fmaf(exp2f(dt * A2r[10]), xs[10], duv * cB2.z);
        xs[11] = fmaf(exp2f(dt * A2r[11]), xs[11], duv * cB2.w);
        xs[12] = fmaf(exp2f(dt * A2r[12]), xs[12], duv * cB3.x);
        xs[13] = fmaf(exp2f(dt * A2r[13]), xs[13], duv * cB3.y);
        xs[14] = fmaf(exp2f(dt * A2r[14]), xs[14], duv * cB3.z);
        xs[15] = fmaf(exp2f(dt * A2r[15]), xs[15], duv * cB3.w);
        float y = xs[0] * cC0.x;
        y = fmaf(xs[1],  cC0.y, y);
        y = fmaf(xs[2],  cC0.z, y);
        y = fmaf(xs[3],  cC0.w, y);
        y = fmaf(xs[4],  cC1.x, y);
        y = fmaf(xs[5],  cC1.y, y);
        y = fmaf(xs[6],  cC1.z, y);
        y = fmaf(xs[7],  cC1.w, y);
        y = fmaf(xs[8],  cC2.x, y);
        y = fmaf(xs[9],  cC2.y, y);
        y = fmaf(xs[10], cC2.z, y);
        y = fmaf(xs[11], cC2.w, y);
        y = fmaf(xs[12], cC3.x, y);
        y = fmaf(xs[13], cC3.y, y);
        y = fmaf(xs[14], cC3.z, y);
        y = fmaf(xs[15], cC3.w, y);
        y = fmaf(cu, Dpd, y);
        resy[(segbase + tl) * D + d] = y * (cg * sigmoidf_(cg));
    }
}

// out_proj + residual via 3-term split-bf16 MFMA: h[t] += y[t] @ out_w.T
__global__ __launch_bounds__(256) void k_outproj(
    const float* __restrict__ y, const short* __restrict__ wh, const short* __restrict__ wl,
    float* __restrict__ h)
{
    __shared__ __align__(16) short ysh[32 * ZS];
    __shared__ __align__(16) short ysl[32 * ZS];
    const int tid = threadIdx.x;
    const int wv = tid >> 6, lane = tid & 63;
    const size_t tb = (size_t)blockIdx.x * 32;

    #pragma unroll
    for (int i = 0; i < 4; ++i) {
        int idx = tid + i * 256;
        int row = idx >> 5, c4 = idx & 31;
        float4 v = *(const float4*)&y[(tb + row) * D + c4 * 4];
        short h0 = f2bf(v.x), h1 = f2bf(v.y), h2 = f2bf(v.z), h3 = f2bf(v.w);
        *(short4*)&ysh[row * ZS + c4 * 4] = make_short4(h0, h1, h2, h3);
        *(short4*)&ysl[row * ZS + c4 * 4] = make_short4(
            f2bf(v.x - bf2f(h0)), f2bf(v.y - bf2f(h1)),
            f2bf(v.z - bf2f(h2)), f2bf(v.w - bf2f(h3)));
    }

    const int colb = wv * 32 + (lane & 15);
    const int kb = (lane >> 4) * 8;
    bf16x8 bw[2][4];
    #pragma unroll
    for (int ct = 0; ct < 2; ++ct)
        #pragma unroll
        for (int kf = 0; kf < 4; ++kf)
            bw[ct][kf] = *(const bf16x8*)&wh[(colb + ct * 16) * 128 + kf * 32 + kb];
    __syncthreads();

    f32x4 acc[2][2];
    #pragma unroll
    for (int b = 0; b < 2; ++b)
        #pragma unroll
        for (int ct = 0; ct < 2; ++ct)
            acc[b][ct] = (f32x4){0.f, 0.f, 0.f, 0.f};

    #pragma unroll
    for (int b = 0; b < 2; ++b) {
        bf16x8 ah[4], al[4];
        const int rbase = (b * 16 + (lane & 15)) * ZS + kb;
        #pragma unroll
        for (int kf = 0; kf < 4; ++kf) {
            ah[kf] = *(const bf16x8*)&ysh[rbase + kf * 32];
            al[kf] = *(const bf16x8*)&ysl[rbase + kf * 32];
        }
        #pragma unroll
        for (int ct = 0; ct < 2; ++ct)
            #pragma unroll
            for (int kf = 0; kf < 4; ++kf) {
                acc[b][ct] = __builtin_amdgcn_mfma_f32_16x16x32_bf16(ah[kf], bw[ct][kf], acc[b][ct], 0, 0, 0);
                acc[b][ct] = __builtin_amdgcn_mfma_f32_16x16x32_bf16(al[kf], bw[ct][kf], acc[b][ct], 0, 0, 0);
            }
    }
    #pragma unroll
    for (int ct = 0; ct < 2; ++ct)
        #pragma unroll
        for (int kf = 0; kf < 4; ++kf)
            bw[ct][kf] = *(const bf16x8*)&wl[(colb + ct * 16) * 128 + kf * 32 + kb];
    #pragma unroll
    for (int b = 0; b < 2; ++b) {
        bf16x8 ah[4];
        const int rbase = (b * 16 + (lane & 15)) * ZS + kb;
        #pragma unroll
        for (int kf = 0; kf < 4; ++kf)
            ah[kf] = *(const bf16x8*)&ysh[rbase + kf * 32];
        #pragma unroll
        for (int ct = 0; ct < 2; ++ct)
            #pragma unroll
            for (int kf = 0; kf < 4; ++kf)
                acc[b][ct] = __builtin_amdgcn_mfma_f32_16x16x32_bf16(ah[kf], bw[ct][kf], acc[b][ct], 0, 0, 0);
    }

    #pragma unroll
    for (int b = 0; b < 2; ++b)
        #pragma unroll
        for (int ct = 0; ct < 2; ++ct) {
            const int col = wv * 32 + ct * 16 + (lane & 15);
            #pragma unroll
            for (int i = 0; i < 4; ++i) {
                int row = b * 16 + ((lane >> 4) << 2) + i;
                size_t o = (tb + row) * D + col;
                h[o] += acc[b][ct][i];
            }
        }
}

// out[t] = h[t] . outp_w + outp_b  (one wave per token)
__global__ __launch_bounds__(256) void k_final(
    const float* __restrict__ h, const float* __restrict__ outp_w,
    const float* __restrict__ outp_b, float* __restrict__ out)
{
    const int tid = threadIdx.x;
    const int lane = tid & 63;
    const size_t tok = (size_t)blockIdx.x * 4 + (tid >> 6);
    float a = h[tok * D + lane] * outp_w[lane] + h[tok * D + lane + 64] * outp_w[lane + 64];
    #pragma unroll
    for (int m = 1; m < 64; m <<= 1) a += __shfl_xor(a, m);
    if (lane == 0) out[tok] = a + outp_b[0];
}

extern "C" void kernel_launch(void* const* d_in, const int* in_sizes, int n_in,
                              void* d_out, int out_size, void* d_ws, size_t ws_size,
                              hipStream_t stream)
{
    const float* x      = (const float*)d_in[0];
    const float* inp_w  = (const float*)d_in[1];
    const float* inp_b  = (const float*)d_in[2];
    const float* outp_w = (const float*)d_in[3];
    const float* outp_b = (const float*)d_in[4];
    const float* ln_g   = (const float*)d_in[5];
    const float* ln_b   = (const float*)d_in[6];
    const float* in_w   = (const float*)d_in[7];
    const float* conv_w = (const float*)d_in[8];
    const float* conv_b = (const float*)d_in[9];
    const float* xp_w   = (const float*)d_in[10];
    const float* dp_w   = (const float*)d_in[11];
    const float* dp_b   = (const float*)d_in[12];
    const float* A_log  = (const float*)d_in[13];
    const float* Dp     = (const float*)d_in[14];
    const float* out_w  = (const float*)d_in[15];

    float* ws = (float*)d_ws;
    size_t off = 0;
    float* h      = ws + off; off += (size_t)NTOK * D;
    float* xc     = ws + off; off += (size_t)NTOK * D;
    float* resy   = ws + off; off += (size_t)NTOK * D;
    float* bc     = ws + off; off += (size_t)NTOK * 32;
    float* dlt    = ws + off; off += (size_t)NTOK * 8;
    float* Pbuf   = ws + off; off += 128 * SEG * 2048;
    float* Fbuf   = ws + off; off += 128 * SEG * 2048;
    short* in_wBh = (short*)(ws + off); off += 4 * 256 * 128 / 2;
    short* in_wBl = (short*)(ws + off); off += 4 * 256 * 128 / 2;
    short* out_wBh= (short*)(ws + off); off += 4 * 128 * 128 / 2;
    short* out_wBl= (short*)(ws + off); off += 4 * 128 * 128 / 2;
    short* xp_wBh = (short*)(ws + off); off += 4 * 48 * 128 / 2;
    short* xp_wBl = (short*)(ws + off); off += 4 * 48 * 128 / 2;
    float* A2     = ws + off; off += 4 * 128 * 16;
    if (ws_size < off * sizeof(float)) return;  // workspace too small -> fail visibly

    // prep
    k_prepw<<<(4 * 256 * 128 + 255) / 256, 256, 0, stream>>>(in_w, in_wBh, in_wBl, 4 * 256 * 128);
    k_prepw<<<(4 * 128 * 128 + 255) / 256, 256, 0, stream>>>(out_w, out_wBh, out_wBl, 4 * 128 * 128);
    k_prepw_xp<<<(4 * 48 * 128 + 255) / 256, 256, 0, stream>>>(xp_w, xp_wBh, xp_wBl);
    k_a2<<<(4 * 128 * 16 + 255) / 256, 256, 0, stream>>>(A_log, A2, 4 * 128 * 16);
    k_init_h<<<NTOK * D / 256, 256, 0, stream>>>(x, inp_w, inp_b, h);

    for (int l = 0; l < 4; ++l) {
        k_ln_inproj_conv<<<NTOK / 32, 256, 0, stream>>>(
            h, ln_g + l * 128, ln_b + l * 128,
            in_wBh + l * 256 * 128, in_wBl + l * 256 * 128,
            xp_wBh + l * 48 * 128, xp_wBl + l * 48 * 128,
            conv_w + l * 128 * 3, conv_b + l * 128, xc, resy, bc, dlt);
        k_scan1<<<512, 256, 0, stream>>>(xc, bc, dlt, dp_w + l * 128 * 8, dp_b + l * 128,
                                         A2 + l * 128 * 16, Pbuf, Fbuf);
        k_scan2<<<512, 256, 0, stream>>>(xc, bc, dlt, dp_w + l * 128 * 8, dp_b + l * 128,
                                         A2 + l * 128 * 16, Dp + l * 128, Pbuf, Fbuf, resy);
        k_outproj<<<NTOK / 32, 256, 0, stream>>>(resy, out_wBh + l * 128 * 128,
                                                 out_wBl + l * 128 * 128, h);
    }
    k_final<<<NTOK / 4, 256, 0, stream>>>(h, outp_w, outp_b, (float*)d_out);
}

// Round 18
// 1584.202 us; speedup vs baseline: 1.0348x; 1.0348x over previous
//
#include <hip/hip_runtime.h>
#include <math.h>

#define D 128
#define NSTATE 16
#define DR 8
#define T_SEQ 1024
#define NTOK 131072  // 128 sequences * 1024 tokens
#define SEG 16       // segments per sequence (parallel scan)
#define SEGLEN 64    // T_SEQ / SEG
#define ZS 136       // bf16 elems per z row (128 + 8 pad -> 272B stride)
#define XRS2 132     // f32 elems per xr row (128 + 4 pad)

typedef __attribute__((ext_vector_type(8))) short bf16x8;
typedef __attribute__((ext_vector_type(4))) float f32x4;

#define LOG2E 1.44269504088896340736f
#define LN2   0.69314718055994530942f

// fast sigmoid: 1/(1+2^(-x*log2e)) via v_exp + v_rcp (~1 ulp)
__device__ __forceinline__ float sigmoidf_(float x) {
    return __builtin_amdgcn_rcpf(1.0f + exp2f(-x * LOG2E));
}
// fast softplus: ln2 * log2(1 + 2^(x*log2e)) via v_exp + v_log
__device__ __forceinline__ float softplusf_(float x) {
    float t = LN2 * __builtin_amdgcn_logf(1.0f + exp2f(x * LOG2E));
    return (x > 20.0f) ? x : t;
}
__device__ __forceinline__ short f2bf(float f) {   // RNE float->bf16
    union { float f; unsigned u; } v; v.f = f;
    unsigned r = v.u + 0x7FFFu + ((v.u >> 16) & 1u);
    return (short)(r >> 16);
}
__device__ __forceinline__ float bf2f(short s) {
    union { unsigned u; float f; } v; v.u = ((unsigned)(unsigned short)s) << 16;
    return v.f;
}

// ---------------- prep kernels ----------------

// f32 -> bf16 hi/lo split, elementwise (layout preserved)
__global__ void k_prepw(const float* __restrict__ src, short* __restrict__ hi,
                        short* __restrict__ lo, int n) {
    int i = blockIdx.x * 256 + threadIdx.x;
    if (i < n) {
        float f = src[i];
        short hh = f2bf(f);
        hi[i] = hh;
        lo[i] = f2bf(f - bf2f(hh));
    }
}

// xp_w (L,40,128) -> padded (L,48,128) bf16 hi/lo, rows 40..47 zero
__global__ void k_prepw_xp(const float* __restrict__ src, short* __restrict__ hi,
                           short* __restrict__ lo) {
    int i = blockIdx.x * 256 + threadIdx.x;     // over 4*48*128
    if (i >= 4 * 48 * 128) return;
    int l = i / (48 * 128);
    int rem = i - l * 48 * 128;
    int j = rem >> 7, k = rem & 127;
    float f = (j < 40) ? src[(l * 40 + j) * 128 + k] : 0.f;
    short hh = f2bf(f);
    hi[i] = hh;
    lo[i] = f2bf(f - bf2f(hh));
}

// A2 = -exp(A_log) * log2(e)
__global__ void k_a2(const float* __restrict__ A_log, float* __restrict__ A2, int total) {
    int idx = blockIdx.x * blockDim.x + threadIdx.x;
    if (idx < total) A2[idx] = -__expf(A_log[idx]) * LOG2E;
}

// h[tok][d] = x[tok] * inp_w[d] + inp_b[d]
__global__ void k_init_h(const float* __restrict__ x, const float* __restrict__ inp_w,
                         const float* __restrict__ inp_b, float* __restrict__ h) {
    int idx = blockIdx.x * blockDim.x + threadIdx.x;
    int tok = idx >> 7;
    int d = idx & 127;
    h[idx] = x[tok] * inp_w[d] + inp_b[d];
}

// ---------------- per-layer kernels ----------------
// Fused LN + in_proj (3-term split-bf16 MFMA) + causal conv(k=3) + SiLU
// + x_proj (second MFMA stage) -> xc, res, bc, dlt. Coalesced flush via LDS.
__global__ __launch_bounds__(256) void k_ln_inproj_conv(
    const float* __restrict__ h, const float* __restrict__ ln_g, const float* __restrict__ ln_b,
    const short* __restrict__ wh, const short* __restrict__ wl,   // in_proj (256,128) hi/lo
    const short* __restrict__ xph, const short* __restrict__ xpl, // x_proj padded (48,128) hi/lo
    const float* __restrict__ conv_w, const float* __restrict__ conv_b,
    float* __restrict__ xc, float* __restrict__ res,
    float* __restrict__ bc, float* __restrict__ dlt)
{
    __shared__ __align__(16) short zsh[48 * ZS];
    __shared__ __align__(16) short zsl[48 * ZS];
    __shared__ __align__(16) float xr[34 * XRS2];
    __shared__ __align__(16) float dbc_l[32][52];   // stage-2 out (40 used, 52 stride)
    const int tid = threadIdx.x;
    const int wv = tid >> 6, lane = tid & 63;
    const int tstart = blockIdx.x * 32;
    const int tin = tstart & (T_SEQ - 1);

    // Phase A: LayerNorm rows 0..33 -> bf16 hi/lo
    for (int r = wv; r < 34; r += 4) {
        int tr = tin + r - 2;
        if (tr < 0) {
            zsh[r * ZS + lane] = 0; zsh[r * ZS + lane + 64] = 0;
            zsl[r * ZS + lane] = 0; zsl[r * ZS + lane + 64] = 0;
            continue;
        }
        size_t row = (size_t)(tstart + r - 2) * D;
        float a = h[row + lane];
        float b = h[row + lane + 64];
        float s = a + b, ss = a * a + b * b;
        #pragma unroll
        for (int m = 1; m < 64; m <<= 1) { s += __shfl_xor(s, m); ss += __shfl_xor(ss, m); }
        float mu = s * (1.0f / 128.0f);
        float var = ss * (1.0f / 128.0f) - mu * mu;
        float rstd = rsqrtf(var + 1e-5f);
        float z0 = (a - mu) * rstd * ln_g[lane]      + ln_b[lane];
        float z1 = (b - mu) * rstd * ln_g[lane + 64] + ln_b[lane + 64];
        short h0 = f2bf(z0), h1 = f2bf(z1);
        zsh[r * ZS + lane]      = h0;
        zsh[r * ZS + lane + 64] = h1;
        zsl[r * ZS + lane]      = f2bf(z0 - bf2f(h0));
        zsl[r * ZS + lane + 64] = f2bf(z1 - bf2f(h1));
    }
    for (int i = tid; i < 14 * 128; i += 256) {
        int r = 34 + (i >> 7), c = i & 127;
        zsh[r * ZS + c] = 0;
        zsl[r * ZS + c] = 0;
    }

    // B panel (hi) -> registers
    const int colb = wv * 64 + (lane & 15);
    const int kb = (lane >> 4) * 8;
    bf16x8 bw[4][4];
    #pragma unroll
    for (int ct = 0; ct < 4; ++ct)
        #pragma unroll
        for (int kf = 0; kf < 4; ++kf)
            bw[ct][kf] = *(const bf16x8*)&wh[(colb + ct * 16) * 128 + kf * 32 + kb];
    __syncthreads();

    f32x4 acc[3][4];
    #pragma unroll
    for (int b = 0; b < 3; ++b)
        #pragma unroll
        for (int ct = 0; ct < 4; ++ct)
            acc[b][ct] = (f32x4){0.f, 0.f, 0.f, 0.f};

    // Pass 1: (a_hi + a_lo) * b_hi
    #pragma unroll
    for (int b = 0; b < 3; ++b) {
        bf16x8 ah[4], al[4];
        const int rbase = (b * 16 + (lane & 15)) * ZS + kb;
        #pragma unroll
        for (int kf = 0; kf < 4; ++kf) {
            ah[kf] = *(const bf16x8*)&zsh[rbase + kf * 32];
            al[kf] = *(const bf16x8*)&zsl[rbase + kf * 32];
        }
        #pragma unroll
        for (int ct = 0; ct < 4; ++ct)
            #pragma unroll
            for (int kf = 0; kf < 4; ++kf) {
                acc[b][ct] = __builtin_amdgcn_mfma_f32_16x16x32_bf16(ah[kf], bw[ct][kf], acc[b][ct], 0, 0, 0);
                acc[b][ct] = __builtin_amdgcn_mfma_f32_16x16x32_bf16(al[kf], bw[ct][kf], acc[b][ct], 0, 0, 0);
            }
    }
    // Pass 2: a_hi * b_lo
    #pragma unroll
    for (int ct = 0; ct < 4; ++ct)
        #pragma unroll
        for (int kf = 0; kf < 4; ++kf)
            bw[ct][kf] = *(const bf16x8*)&wl[(colb + ct * 16) * 128 + kf * 32 + kb];
    #pragma unroll
    for (int b = 0; b < 3; ++b) {
        bf16x8 ah[4];
        const int rbase = (b * 16 + (lane & 15)) * ZS + kb;
        #pragma unroll
        for (int kf = 0; kf < 4; ++kf)
            ah[kf] = *(const bf16x8*)&zsh[rbase + kf * 32];
        #pragma unroll
        for (int ct = 0; ct < 4; ++ct)
            #pragma unroll
            for (int kf = 0; kf < 4; ++kf)
                acc[b][ct] = __builtin_amdgcn_mfma_f32_16x16x32_bf16(ah[kf], bw[ct][kf], acc[b][ct], 0, 0, 0);
    }

    // conv-half acc (waves 0-1) -> xr; gate half stays in registers
    if (wv < 2) {
        #pragma unroll
        for (int b = 0; b < 3; ++b)
            #pragma unroll
            for (int ct = 0; ct < 4; ++ct) {
                const int col = wv * 64 + ct * 16 + (lane & 15);
                #pragma unroll
                for (int i = 0; i < 4; ++i) {
                    int row = b * 16 + ((lane >> 4) << 2) + i;
                    if (row < 34) xr[row * XRS2 + col] = acc[b][ct][i];
                }
            }
    }
    __syncthreads();

    // Epilogue: conv+silu, 256 threads (channel = tid&127, token half = tid>>7)
    {
        int ch = tid & 127, s0 = (tid >> 7) * 16;
        float c0 = conv_w[ch * 3 + 0], c1 = conv_w[ch * 3 + 1], c2 = conv_w[ch * 3 + 2];
        float cb = conv_b[ch];
        float v0 = xr[(s0 + 0) * XRS2 + ch], v1 = xr[(s0 + 1) * XRS2 + ch];
        #pragma unroll
        for (int s = 0; s < 16; ++s) {
            float v2 = xr[(s0 + s + 2) * XRS2 + ch];
            float v = v0 * c0 + v1 * c1 + v2 * c2 + cb;
            v = v * sigmoidf_(v);
            xc[(size_t)(tstart + s0 + s) * D + ch] = v;
            short hh = f2bf(v);
            zsh[(s0 + s) * ZS + ch] = hh;
            zsl[(s0 + s) * ZS + ch] = f2bf(v - bf2f(hh));
            v0 = v1; v1 = v2;
        }
    }
    __syncthreads();

    // gate-half acc (waves 2-3) -> xr rows 2..33 (xr conv columns free now);
    if (wv >= 2) {
        #pragma unroll
        for (int b = 0; b < 3; ++b)
            #pragma unroll
            for (int ct = 0; ct < 4; ++ct) {
                const int col = (wv - 2) * 64 + ct * 16 + (lane & 15);
                #pragma unroll
                for (int i = 0; i < 4; ++i) {
                    int row = b * 16 + ((lane >> 4) << 2) + i;
                    if (row >= 2 && row < 34) xr[row * XRS2 + col] = acc[b][ct][i];
                }
            }
    }
    // Stage 2 MFMA: dbc = xc @ xp_w.T (M=32, N=48 padded, K=128), 3-term split.
    for (int tile = wv; tile < 6; tile += 4) {
        const int b = tile & 1, ct = tile >> 1;
        const int jcol = ct * 16 + (lane & 15);
        const int rbase = (b * 16 + (lane & 15)) * ZS + kb;
        bf16x8 ah[4], al[4], bh[4];
        #pragma unroll
        for (int kf = 0; kf < 4; ++kf) {
            ah[kf] = *(const bf16x8*)&zsh[rbase + kf * 32];
            al[kf] = *(const bf16x8*)&zsl[rbase + kf * 32];
            bh[kf] = *(const bf16x8*)&xph[jcol * 128 + kf * 32 + kb];
        }
        f32x4 a2 = (f32x4){0.f, 0.f, 0.f, 0.f};
        #pragma unroll
        for (int kf = 0; kf < 4; ++kf) {
            a2 = __builtin_amdgcn_mfma_f32_16x16x32_bf16(ah[kf], bh[kf], a2, 0, 0, 0);
            a2 = __builtin_amdgcn_mfma_f32_16x16x32_bf16(al[kf], bh[kf], a2, 0, 0, 0);
        }
        #pragma unroll
        for (int kf = 0; kf < 4; ++kf) {
            bh[kf] = *(const bf16x8*)&xpl[jcol * 128 + kf * 32 + kb];
            a2 = __builtin_amdgcn_mfma_f32_16x16x32_bf16(ah[kf], bh[kf], a2, 0, 0, 0);
        }
        #pragma unroll
        for (int i = 0; i < 4; ++i) {
            int t = b * 16 + ((lane >> 4) << 2) + i;
            dbc_l[t][jcol] = a2[i];
        }
    }
    __syncthreads();

    // Coalesced flush: res (32 x 512B), bc (4KB contig), dlt (1KB contig)
    for (int fi = tid; fi < 1024; fi += 256) {
        int r = fi >> 5, c4 = fi & 31;
        *(float4*)&res[(size_t)(tstart + r) * D + c4 * 4] =
            *(const float4*)&xr[(r + 2) * XRS2 + c4 * 4];
    }
    {
        int t = tid >> 3, q = tid & 7;
        *(float4*)&bc[(size_t)(tstart + t) * 32 + q * 4] = *(const float4*)&dbc_l[t][8 + q * 4];
    }
    if (tid < 64) {
        int t = tid >> 1, j4 = tid & 1;
        *(float4*)&dlt[(size_t)(tstart + t) * 8 + j4 * 4] = *(const float4*)&dbc_l[t][j4 * 4];
    }
}

// ---- LDS-free streaming selective scan: one thread per (segment, d) row ----
// SEG=16 (2048 segments) for occupancy; S stored instead of P (P recomputed).
// No __shared__, no barriers. Grid: 1024 blocks x 256 thr = 2048 segments.
// Pass 1: scan from x=0 -> F (16 states), S = sum(dt).
__global__ __launch_bounds__(256) void k_scan1(
    const float* __restrict__ xc, const float* __restrict__ bc,
    const float* __restrict__ dlt,
    const float* __restrict__ dp_w, const float* __restrict__ dp_b,
    const float* __restrict__ A2,
    float* __restrict__ Sbuf, float* __restrict__ Fbuf)
{
    const int tid = threadIdx.x;
    const int d = tid & 127;
    const int segid = blockIdx.x * 2 + (tid >> 7);  // 0..2047
    const size_t segbase = (size_t)segid * SEGLEN;  // token index

    float dpw[DR];
    #pragma unroll
    for (int r = 0; r < DR; ++r) dpw[r] = dp_w[d * DR + r];
    const float dpb = dp_b[d];
    float A2r[NSTATE];
    #pragma unroll
    for (int n = 0; n < NSTATE; ++n) A2r[n] = A2[d * NSTATE + n];
    float xs[NSTATE];
    #pragma unroll
    for (int n = 0; n < NSTATE; ++n) xs[n] = 0.f;
    float S = 0.f;

    // prefetch step 0
    float4 dl0 = *(const float4*)&dlt[segbase * 8];
    float4 dl1 = *(const float4*)&dlt[segbase * 8 + 4];
    float4 B0 = *(const float4*)&bc[segbase * 32 + 0];
    float4 B1 = *(const float4*)&bc[segbase * 32 + 4];
    float4 B2 = *(const float4*)&bc[segbase * 32 + 8];
    float4 B3 = *(const float4*)&bc[segbase * 32 + 12];
    float uv = xc[segbase * D + d];

    for (int tl = 0; tl < SEGLEN; ++tl) {
        float4 cd0 = dl0, cd1 = dl1, cB0 = B0, cB1 = B1, cB2 = B2, cB3 = B3;
        float cu = uv;
        if (tl + 1 < SEGLEN) {
            const size_t nt = segbase + tl + 1;
            dl0 = *(const float4*)&dlt[nt * 8];
            dl1 = *(const float4*)&dlt[nt * 8 + 4];
            B0 = *(const float4*)&bc[nt * 32 + 0];
            B1 = *(const float4*)&bc[nt * 32 + 4];
            B2 = *(const float4*)&bc[nt * 32 + 8];
            B3 = *(const float4*)&bc[nt * 32 + 12];
            uv = xc[nt * D + d];
        }
        float v = dpb;
        v = fmaf(cd0.x, dpw[0], v); v = fmaf(cd0.y, dpw[1], v);
        v = fmaf(cd0.z, dpw[2], v); v = fmaf(cd0.w, dpw[3], v);
        v = fmaf(cd1.x, dpw[4], v); v = fmaf(cd1.y, dpw[5], v);
        v = fmaf(cd1.z, dpw[6], v); v = fmaf(cd1.w, dpw[7], v);
        float dt = softplusf_(v);
        float duv = dt * cu;
        S += dt;
        xs[0]  = fmaf(exp2f(dt * A2r[0]),  xs[0],  duv * cB0.x);
        xs[1]  = fmaf(exp2f(dt * A2r[1]),  xs[1],  duv * cB0.y);
        xs[2]  = fmaf(exp2f(dt * A2r[2]),  xs[2],  duv * cB0.z);
        xs[3]  = fmaf(exp2f(dt * A2r[3]),  xs[3],  duv * cB0.w);
        xs[4]  = fmaf(exp2f(dt * A2r[4]),  xs[4],  duv * cB1.x);
        xs[5]  = fmaf(exp2f(dt * A2r[5]),  xs[5],  duv * cB1.y);
        xs[6]  = fmaf(exp2f(dt * A2r[6]),  xs[6],  duv * cB1.z);
        xs[7]  = fmaf(exp2f(dt * A2r[7]),  xs[7],  duv * cB1.w);
        xs[8]  = fmaf(exp2f(dt * A2r[8]),  xs[8],  duv * cB2.x);
        xs[9]  = fmaf(exp2f(dt * A2r[9]),  xs[9],  duv * cB2.y);
        xs[10] = fmaf(exp2f(dt * A2r[10]), xs[10], duv * cB2.z);
        xs[11] = fmaf(exp2f(dt * A2r[11]), xs[11], duv * cB2.w);
        xs[12] = fmaf(exp2f(dt * A2r[12]), xs[12], duv * cB3.x);
        xs[13] = fmaf(exp2f(dt * A2r[13]), xs[13], duv * cB3.y);
        xs[14] = fmaf(exp2f(dt * A2r[14]), xs[14], duv * cB3.z);
        xs[15] = fmaf(exp2f(dt * A2r[15]), xs[15], duv * cB3.w);
    }
    const size_t o = ((size_t)segid * D + d) * NSTATE;
    #pragma unroll
    for (int nq = 0; nq < 4; ++nq)
        *(float4*)&Fbuf[o + nq * 4] =
            make_float4(xs[nq*4], xs[nq*4+1], xs[nq*4+2], xs[nq*4+3]);
    Sbuf[(size_t)segid * D + d] = S;
}

// Pass 2: inline fix-up (P recomputed from S) -> x_init, re-scan;
// y = C.x + u*Dp, gated, -> resy.
__global__ __launch_bounds__(256) void k_scan2(
    const float* __restrict__ xc, const float* __restrict__ bc,
    const float* __restrict__ dlt,
    const float* __restrict__ dp_w, const float* __restrict__ dp_b,
    const float* __restrict__ A2, const float* __restrict__ Dp,
    const float* __restrict__ Sbuf, const float* __restrict__ Fbuf,
    float* __restrict__ resy)
{
    const int tid = threadIdx.x;
    const int d = tid & 127;
    const int segid = blockIdx.x * 2 + (tid >> 7);  // 0..2047
    const int seg = segid & (SEG - 1);
    const int seg0 = segid - seg;                   // first segment of sequence
    const size_t segbase = (size_t)segid * SEGLEN;

    float dpw[DR];
    #pragma unroll
    for (int r = 0; r < DR; ++r) dpw[r] = dp_w[d * DR + r];
    const float dpb = dp_b[d];
    float A2r[NSTATE];
    #pragma unroll
    for (int n = 0; n < NSTATE; ++n) A2r[n] = A2[d * NSTATE + n];
    const float Dpd = Dp[d];

    // inline fix-up: ascending combine x = P_s*x + F_s over predecessors
    float xs[NSTATE];
    #pragma unroll
    for (int n = 0; n < NSTATE; ++n) xs[n] = 0.f;
    for (int s = 0; s < seg; ++s) {
        const int sid = seg0 + s;
        const float Sv = Sbuf[(size_t)sid * D + d];
        const size_t idx = ((size_t)sid * D + d) * NSTATE;
        #pragma unroll
        for (int n = 0; n < NSTATE; ++n) {
            float F = Fbuf[idx + n];
            xs[n] = fmaf(exp2f(A2r[n] * Sv), xs[n], F);
        }
    }

    // prefetch step 0
    float4 dl0 = *(const float4*)&dlt[segbase * 8];
    float4 dl1 = *(const float4*)&dlt[segbase * 8 + 4];
    float4 B0 = *(const float4*)&bc[segbase * 32 + 0];
    float4 B1 = *(const float4*)&bc[segbase * 32 + 4];
    float4 B2 = *(const float4*)&bc[segbase * 32 + 8];
    float4 B3 = *(const float4*)&bc[segbase * 32 + 12];
    float4 C0 = *(const float4*)&bc[segbase * 32 + 16];
    float4 C1 = *(const float4*)&bc[segbase * 32 + 20];
    float4 C2 = *(const float4*)&bc[segbase * 32 + 24];
    float4 C3 = *(const float4*)&bc[segbase * 32 + 28];
    float uv = xc[segbase * D + d];
    float rg = resy[segbase * D + d];

    for (int tl = 0; tl < SEGLEN; ++tl) {
        float4 cd0 = dl0, cd1 = dl1;
        float4 cB0 = B0, cB1 = B1, cB2 = B2, cB3 = B3;
        float4 cC0 = C0, cC1 = C1, cC2 = C2, cC3 = C3;
        float cu = uv, cg = rg;
        if (tl + 1 < SEGLEN) {
            const size_t nt = segbase + tl + 1;
            dl0 = *(const float4*)&dlt[nt * 8];
            dl1 = *(const float4*)&dlt[nt * 8 + 4];
            B0 = *(const float4*)&bc[nt * 32 + 0];
            B1 = *(const float4*)&bc[nt * 32 + 4];
            B2 = *(const float4*)&bc[nt * 32 + 8];
            B3 = *(const float4*)&bc[nt * 32 + 12];
            C0 = *(const float4*)&bc[nt * 32 + 16];
            C1 = *(const float4*)&bc[nt * 32 + 20];
            C2 = *(const float4*)&bc[nt * 32 + 24];
            C3 = *(const float4*)&bc[nt * 32 + 28];
            uv = xc[nt * D + d];
            rg = resy[nt * D + d];
        }
        float v = dpb;
        v = fmaf(cd0.x, dpw[0], v); v = fmaf(cd0.y, dpw[1], v);
        v = fmaf(cd0.z, dpw[2], v); v = fmaf(cd0.w, dpw[3], v);
        v = fmaf(cd1.x, dpw[4], v); v = fmaf(cd1.y, dpw[5], v);
        v = fmaf(cd1.z, dpw[6], v); v = fmaf(cd1.w, dpw[7], v);
        float dt = softplusf_(v);
        float duv = dt * cu;
        xs[0]  = fmaf(exp2f(dt * A2r[0]),  xs[0],  duv * cB0.x);
        xs[1]  = fmaf(exp2f(dt * A2r[1]),  xs[1],  duv * cB0.y);
        xs[2]  = fmaf(exp2f(dt * A2r[2]),  xs[2],  duv * cB0.z);
        xs[3]  = fmaf(exp2f(dt * A2r[3]),  xs[3],  duv * cB0.w);
        xs[4]  = fmaf(exp2f(dt * A2r[4]),  xs[4],  duv * cB1.x);
        xs[5]  = fmaf(exp2f(dt * A2r[5]),  xs[5],  duv * cB1.y);
        xs[6]  = fmaf(exp2f(dt * A2r[6]),  xs[6],  duv * cB1.z);
        xs[7]  = fmaf(exp2f(dt * A2r[7]),  xs[7],  duv * cB1.w);
        xs[8]  = fmaf(exp2f(dt * A2r[8]),  xs[8],  duv * cB2.x);
        xs[9]  = fmaf(exp2f(dt * A2r[9]),  xs[9],  duv * cB2.y);
        xs[10] = fmaf(exp2f(dt * A2r[10]), xs[10], duv * cB2.z);
        xs[11] = fmaf(exp2f(dt * A2r[11]), xs[11], duv * cB2.w);
        xs[12] = fmaf(exp2f(dt * A2r[12]), xs[12], duv * cB3.x);
        xs[13] = fmaf(exp2f(dt * A2r[13]), xs[13], duv * cB3.y);
        xs[14] = fmaf(exp2f(dt * A2r[14]), xs[14], duv * cB3.z);
        xs[15] = fmaf(exp2f(dt * A2r[15]), xs[15], duv * cB3.w);
        float y = xs[0] * cC0.x;
        y = fmaf(xs[1],  cC0.y, y);
        y = fmaf(xs[2],  cC0.z, y);
        y = fmaf(xs[3],  cC0.w, y);
        y = fmaf(xs[4],  cC1.x, y);
        y = fmaf(xs[5],  cC1.y, y);
        y = fmaf(xs[6],  cC1.z, y);
        y = fmaf(xs[7],  cC1.w, y);
        y = fmaf(xs[8],  cC2.x, y);
        y = fmaf(xs[9],  cC2.y, y);
        y = fmaf(xs[10], cC2.z, y);
        y = fmaf(xs[11], cC2.w, y);
        y = fmaf(xs[12], cC3.x, y);
        y = fmaf(xs[13], cC3.y, y);
        y = fmaf(xs[14], cC3.z, y);
        y = fmaf(xs[15], cC3.w, y);
        y = fmaf(cu, Dpd, y);
        resy[(segbase + tl) * D + d] = y * (cg * sigmoidf_(cg));
    }
}

// out_proj + residual via 3-term split-bf16 MFMA: h[t] += y[t] @ out_w.T
__global__ __launch_bounds__(256) void k_outproj(
    const float* __restrict__ y, const short* __restrict__ wh, const short* __restrict__ wl,
    float* __restrict__ h)
{
    __shared__ __align__(16) short ysh[32 * ZS];
    __shared__ __align__(16) short ysl[32 * ZS];
    const int tid = threadIdx.x;
    const int wv = tid >> 6, lane = tid & 63;
    const size_t tb = (size_t)blockIdx.x * 32;

    #pragma unroll
    for (int i = 0; i < 4; ++i) {
        int idx = tid + i * 256;
        int row = idx >> 5, c4 = idx & 31;
        float4 v = *(const float4*)&y[(tb + row) * D + c4 * 4];
        short h0 = f2bf(v.x), h1 = f2bf(v.y), h2 = f2bf(v.z), h3 = f2bf(v.w);
        *(short4*)&ysh[row * ZS + c4 * 4] = make_short4(h0, h1, h2, h3);
        *(short4*)&ysl[row * ZS + c4 * 4] = make_short4(
            f2bf(v.x - bf2f(h0)), f2bf(v.y - bf2f(h1)),
            f2bf(v.z - bf2f(h2)), f2bf(v.w - bf2f(h3)));
    }

    const int colb = wv * 32 + (lane & 15);
    const int kb = (lane >> 4) * 8;
    bf16x8 bw[2][4];
    #pragma unroll
    for (int ct = 0; ct < 2; ++ct)
        #pragma unroll
        for (int kf = 0; kf < 4; ++kf)
            bw[ct][kf] = *(const bf16x8*)&wh[(colb + ct * 16) * 128 + kf * 32 + kb];
    __syncthreads();

    f32x4 acc[2][2];
    #pragma unroll
    for (int b = 0; b < 2; ++b)
        #pragma unroll
        for (int ct = 0; ct < 2; ++ct)
            acc[b][ct] = (f32x4){0.f, 0.f, 0.f, 0.f};

    #pragma unroll
    for (int b = 0; b < 2; ++b) {
        bf16x8 ah[4], al[4];
        const int rbase = (b * 16 + (lane & 15)) * ZS + kb;
        #pragma unroll
        for (int kf = 0; kf < 4; ++kf) {
            ah[kf] = *(const bf16x8*)&ysh[rbase + kf * 32];
            al[kf] = *(const bf16x8*)&ysl[rbase + kf * 32];
        }
        #pragma unroll
        for (int ct = 0; ct < 2; ++ct)
            #pragma unroll
            for (int kf = 0; kf < 4; ++kf) {
                acc[b][ct] = __builtin_amdgcn_mfma_f32_16x16x32_bf16(ah[kf], bw[ct][kf], acc[b][ct], 0, 0, 0);
                acc[b][ct] = __builtin_amdgcn_mfma_f32_16x16x32_bf16(al[kf], bw[ct][kf], acc[b][ct], 0, 0, 0);
            }
    }
    #pragma unroll
    for (int ct = 0; ct < 2; ++ct)
        #pragma unroll
        for (int kf = 0; kf < 4; ++kf)
            bw[ct][kf] = *(const bf16x8*)&wl[(colb + ct * 16) * 128 + kf * 32 + kb];
    #pragma unroll
    for (int b = 0; b < 2; ++b) {
        bf16x8 ah[4];
        const int rbase = (b * 16 + (lane & 15)) * ZS + kb;
        #pragma unroll
        for (int kf = 0; kf < 4; ++kf)
            ah[kf] = *(const bf16x8*)&ysh[rbase + kf * 32];
        #pragma unroll
        for (int ct = 0; ct < 2; ++ct)
            #pragma unroll
            for (int kf = 0; kf < 4; ++kf)
                acc[b][ct] = __builtin_amdgcn_mfma_f32_16x16x32_bf16(ah[kf], bw[ct][kf], acc[b][ct], 0, 0, 0);
    }

    #pragma unroll
    for (int b = 0; b < 2; ++b)
        #pragma unroll
        for (int ct = 0; ct < 2; ++ct) {
            const int col = wv * 32 + ct * 16 + (lane & 15);
            #pragma unroll
            for (int i = 0; i < 4; ++i) {
                int row = b * 16 + ((lane >> 4) << 2) + i;
                size_t o = (tb + row) * D + col;
                h[o] += acc[b][ct][i];
            }
        }
}

// out[t] = h[t] . outp_w + outp_b  (one wave per token)
__global__ __launch_bounds__(256) void k_final(
    const float* __restrict__ h, const float* __restrict__ outp_w,
    const float* __restrict__ outp_b, float* __restrict__ out)
{
    const int tid = threadIdx.x;
    const int lane = tid & 63;
    const size_t tok = (size_t)blockIdx.x * 4 + (tid >> 6);
    float a = h[tok * D + lane] * outp_w[lane] + h[tok * D + lane + 64] * outp_w[lane + 64];
    #pragma unroll
    for (int m = 1; m < 64; m <<= 1) a += __shfl_xor(a, m);
    if (lane == 0) out[tok] = a + outp_b[0];
}

extern "C" void kernel_launch(void* const* d_in, const int* in_sizes, int n_in,
                              void* d_out, int out_size, void* d_ws, size_t ws_size,
                              hipStream_t stream)
{
    const float* x      = (const float*)d_in[0];
    const float* inp_w  = (const float*)d_in[1];
    const float* inp_b  = (const float*)d_in[2];
    const float* outp_w = (const float*)d_in[3];
    const float* outp_b = (const float*)d_in[4];
    const float* ln_g   = (const float*)d_in[5];
    const float* ln_b   = (const float*)d_in[6];
    const float* in_w   = (const float*)d_in[7];
    const float* conv_w = (const float*)d_in[8];
    const float* conv_b = (const float*)d_in[9];
    const float* xp_w   = (const float*)d_in[10];
    const float* dp_w   = (const float*)d_in[11];
    const float* dp_b   = (const float*)d_in[12];
    const float* A_log  = (const float*)d_in[13];
    const float* Dp     = (const float*)d_in[14];
    const float* out_w  = (const float*)d_in[15];

    float* ws = (float*)d_ws;
    size_t off = 0;
    float* h      = ws + off; off += (size_t)NTOK * D;
    float* xc     = ws + off; off += (size_t)NTOK * D;
    float* resy   = ws + off; off += (size_t)NTOK * D;
    float* bc     = ws + off; off += (size_t)NTOK * 32;
    float* dlt    = ws + off; off += (size_t)NTOK * 8;
    float* Fbuf   = ws + off; off += 128 * SEG * 2048;   // 2048 segs x 128 d x 16 n
    float* Sbuf   = ws + off; off += 128 * SEG * 128;    // 2048 segs x 128 d
    short* in_wBh = (short*)(ws + off); off += 4 * 256 * 128 / 2;
    short* in_wBl = (short*)(ws + off); off += 4 * 256 * 128 / 2;
    short* out_wBh= (short*)(ws + off); off += 4 * 128 * 128 / 2;
    short* out_wBl= (short*)(ws + off); off += 4 * 128 * 128 / 2;
    short* xp_wBh = (short*)(ws + off); off += 4 * 48 * 128 / 2;
    short* xp_wBl = (short*)(ws + off); off += 4 * 48 * 128 / 2;
    float* A2     = ws + off; off += 4 * 128 * 16;
    if (ws_size < off * sizeof(float)) return;  // workspace too small -> fail visibly

    // prep
    k_prepw<<<(4 * 256 * 128 + 255) / 256, 256, 0, stream>>>(in_w, in_wBh, in_wBl, 4 * 256 * 128);
    k_prepw<<<(4 * 128 * 128 + 255) / 256, 256, 0, stream>>>(out_w, out_wBh, out_wBl, 4 * 128 * 128);
    k_prepw_xp<<<(4 * 48 * 128 + 255) / 256, 256, 0, stream>>>(xp_w, xp_wBh, xp_wBl);
    k_a2<<<(4 * 128 * 16 + 255) / 256, 256, 0, stream>>>(A_log, A2, 4 * 128 * 16);
    k_init_h<<<NTOK * D / 256, 256, 0, stream>>>(x, inp_w, inp_b, h);

    for (int l = 0; l < 4; ++l) {
        k_ln_inproj_conv<<<NTOK / 32, 256, 0, stream>>>(
            h, ln_g + l * 128, ln_b + l * 128,
            in_wBh + l * 256 * 128, in_wBl + l * 256 * 128,
            xp_wBh + l * 48 * 128, xp_wBl + l * 48 * 128,
            conv_w + l * 128 * 3, conv_b + l * 128, xc, resy, bc, dlt);
        k_scan1<<<1024, 256, 0, stream>>>(xc, bc, dlt, dp_w + l * 128 * 8, dp_b + l * 128,
                                          A2 + l * 128 * 16, Sbuf, Fbuf);
        k_scan2<<<1024, 256, 0, stream>>>(xc, bc, dlt, dp_w + l * 128 * 8, dp_b + l * 128,
                                          A2 + l * 128 * 16, Dp + l * 128, Sbuf, Fbuf, resy);
        k_outproj<<<NTOK / 32, 256, 0, stream>>>(resy, out_wBh + l * 128 * 128,
                                                 out_wBl + l * 128 * 128, h);
    }
    k_final<<<NTOK / 4, 256, 0, stream>>>(h, outp_w, outp_b, (float*)d_out);
}

// Round 19
// 1565.041 us; speedup vs baseline: 1.0475x; 1.0122x over previous
//
#include <hip/hip_runtime.h>
#include <math.h>

#define D 128
#define NSTATE 16
#define DR 8
#define T_SEQ 1024
#define NTOK 131072  // 128 sequences * 1024 tokens
#define SEG 16       // segments per sequence (parallel scan)
#define SEGLEN 64    // T_SEQ / SEG
#define ZS 136       // bf16 elems per z row (128 + 8 pad -> 272B stride)
#define XRS2 132     // f32 elems per xr row (128 + 4 pad)

typedef __attribute__((ext_vector_type(8))) short bf16x8;
typedef __attribute__((ext_vector_type(4))) float f32x4;

#define LOG2E 1.44269504088896340736f
#define LN2   0.69314718055994530942f

// fast sigmoid: 1/(1+2^(-x*log2e)) via v_exp + v_rcp (~1 ulp)
__device__ __forceinline__ float sigmoidf_(float x) {
    return __builtin_amdgcn_rcpf(1.0f + exp2f(-x * LOG2E));
}
// fast softplus: ln2 * log2(1 + 2^(x*log2e)) via v_exp + v_log
__device__ __forceinline__ float softplusf_(float x) {
    float t = LN2 * __builtin_amdgcn_logf(1.0f + exp2f(x * LOG2E));
    return (x > 20.0f) ? x : t;
}
__device__ __forceinline__ short f2bf(float f) {   // RNE float->bf16
    union { float f; unsigned u; } v; v.f = f;
    unsigned r = v.u + 0x7FFFu + ((v.u >> 16) & 1u);
    return (short)(r >> 16);
}
__device__ __forceinline__ float bf2f(short s) {
    union { unsigned u; float f; } v; v.u = ((unsigned)(unsigned short)s) << 16;
    return v.f;
}

// ---------------- prep kernels ----------------

// f32 -> bf16 hi/lo split, elementwise (layout preserved)
__global__ void k_prepw(const float* __restrict__ src, short* __restrict__ hi,
                        short* __restrict__ lo, int n) {
    int i = blockIdx.x * 256 + threadIdx.x;
    if (i < n) {
        float f = src[i];
        short hh = f2bf(f);
        hi[i] = hh;
        lo[i] = f2bf(f - bf2f(hh));
    }
}

// xp_w (L,40,128) -> padded (L,48,128) bf16 hi/lo, rows 40..47 zero
__global__ void k_prepw_xp(const float* __restrict__ src, short* __restrict__ hi,
                           short* __restrict__ lo) {
    int i = blockIdx.x * 256 + threadIdx.x;     // over 4*48*128
    if (i >= 4 * 48 * 128) return;
    int l = i / (48 * 128);
    int rem = i - l * 48 * 128;
    int j = rem >> 7, k = rem & 127;
    float f = (j < 40) ? src[(l * 40 + j) * 128 + k] : 0.f;
    short hh = f2bf(f);
    hi[i] = hh;
    lo[i] = f2bf(f - bf2f(hh));
}

// A2 = -exp(A_log) * log2(e)
__global__ void k_a2(const float* __restrict__ A_log, float* __restrict__ A2, int total) {
    int idx = blockIdx.x * blockDim.x + threadIdx.x;
    if (idx < total) A2[idx] = -__expf(A_log[idx]) * LOG2E;
}

// h[tok][d] = x[tok] * inp_w[d] + inp_b[d]
__global__ void k_init_h(const float* __restrict__ x, const float* __restrict__ inp_w,
                         const float* __restrict__ inp_b, float* __restrict__ h) {
    int idx = blockIdx.x * blockDim.x + threadIdx.x;
    int tok = idx >> 7;
    int d = idx & 127;
    h[idx] = x[tok] * inp_w[d] + inp_b[d];
}

// ---------------- per-layer kernels ----------------
// Fused LN + in_proj (3-term split-bf16 MFMA) + causal conv(k=3) + SiLU
// + x_proj (second MFMA stage) -> xc, res, bc, dlt. Coalesced flush via LDS.
__global__ __launch_bounds__(256) void k_ln_inproj_conv(
    const float* __restrict__ h, const float* __restrict__ ln_g, const float* __restrict__ ln_b,
    const short* __restrict__ wh, const short* __restrict__ wl,   // in_proj (256,128) hi/lo
    const short* __restrict__ xph, const short* __restrict__ xpl, // x_proj padded (48,128) hi/lo
    const float* __restrict__ conv_w, const float* __restrict__ conv_b,
    float* __restrict__ xc, float* __restrict__ res,
    float* __restrict__ bc, float* __restrict__ dlt)
{
    __shared__ __align__(16) short zsh[48 * ZS];
    __shared__ __align__(16) short zsl[48 * ZS];
    __shared__ __align__(16) float xr[34 * XRS2];
    __shared__ __align__(16) float dbc_l[32][52];   // stage-2 out (40 used, 52 stride)
    const int tid = threadIdx.x;
    const int wv = tid >> 6, lane = tid & 63;
    const int tstart = blockIdx.x * 32;
    const int tin = tstart & (T_SEQ - 1);

    // Phase A: LayerNorm rows 0..33 -> bf16 hi/lo
    for (int r = wv; r < 34; r += 4) {
        int tr = tin + r - 2;
        if (tr < 0) {
            zsh[r * ZS + lane] = 0; zsh[r * ZS + lane + 64] = 0;
            zsl[r * ZS + lane] = 0; zsl[r * ZS + lane + 64] = 0;
            continue;
        }
        size_t row = (size_t)(tstart + r - 2) * D;
        float a = h[row + lane];
        float b = h[row + lane + 64];
        float s = a + b, ss = a * a + b * b;
        #pragma unroll
        for (int m = 1; m < 64; m <<= 1) { s += __shfl_xor(s, m); ss += __shfl_xor(ss, m); }
        float mu = s * (1.0f / 128.0f);
        float var = ss * (1.0f / 128.0f) - mu * mu;
        float rstd = rsqrtf(var + 1e-5f);
        float z0 = (a - mu) * rstd * ln_g[lane]      + ln_b[lane];
        float z1 = (b - mu) * rstd * ln_g[lane + 64] + ln_b[lane + 64];
        short h0 = f2bf(z0), h1 = f2bf(z1);
        zsh[r * ZS + lane]      = h0;
        zsh[r * ZS + lane + 64] = h1;
        zsl[r * ZS + lane]      = f2bf(z0 - bf2f(h0));
        zsl[r * ZS + lane + 64] = f2bf(z1 - bf2f(h1));
    }
    for (int i = tid; i < 14 * 128; i += 256) {
        int r = 34 + (i >> 7), c = i & 127;
        zsh[r * ZS + c] = 0;
        zsl[r * ZS + c] = 0;
    }

    // B panel (hi) -> registers
    const int colb = wv * 64 + (lane & 15);
    const int kb = (lane >> 4) * 8;
    bf16x8 bw[4][4];
    #pragma unroll
    for (int ct = 0; ct < 4; ++ct)
        #pragma unroll
        for (int kf = 0; kf < 4; ++kf)
            bw[ct][kf] = *(const bf16x8*)&wh[(colb + ct * 16) * 128 + kf * 32 + kb];
    __syncthreads();

    f32x4 acc[3][4];
    #pragma unroll
    for (int b = 0; b < 3; ++b)
        #pragma unroll
        for (int ct = 0; ct < 4; ++ct)
            acc[b][ct] = (f32x4){0.f, 0.f, 0.f, 0.f};

    // Pass 1: (a_hi + a_lo) * b_hi
    #pragma unroll
    for (int b = 0; b < 3; ++b) {
        bf16x8 ah[4], al[4];
        const int rbase = (b * 16 + (lane & 15)) * ZS + kb;
        #pragma unroll
        for (int kf = 0; kf < 4; ++kf) {
            ah[kf] = *(const bf16x8*)&zsh[rbase + kf * 32];
            al[kf] = *(const bf16x8*)&zsl[rbase + kf * 32];
        }
        #pragma unroll
        for (int ct = 0; ct < 4; ++ct)
            #pragma unroll
            for (int kf = 0; kf < 4; ++kf) {
                acc[b][ct] = __builtin_amdgcn_mfma_f32_16x16x32_bf16(ah[kf], bw[ct][kf], acc[b][ct], 0, 0, 0);
                acc[b][ct] = __builtin_amdgcn_mfma_f32_16x16x32_bf16(al[kf], bw[ct][kf], acc[b][ct], 0, 0, 0);
            }
    }
    // Pass 2: a_hi * b_lo
    #pragma unroll
    for (int ct = 0; ct < 4; ++ct)
        #pragma unroll
        for (int kf = 0; kf < 4; ++kf)
            bw[ct][kf] = *(const bf16x8*)&wl[(colb + ct * 16) * 128 + kf * 32 + kb];
    #pragma unroll
    for (int b = 0; b < 3; ++b) {
        bf16x8 ah[4];
        const int rbase = (b * 16 + (lane & 15)) * ZS + kb;
        #pragma unroll
        for (int kf = 0; kf < 4; ++kf)
            ah[kf] = *(const bf16x8*)&zsh[rbase + kf * 32];
        #pragma unroll
        for (int ct = 0; ct < 4; ++ct)
            #pragma unroll
            for (int kf = 0; kf < 4; ++kf)
                acc[b][ct] = __builtin_amdgcn_mfma_f32_16x16x32_bf16(ah[kf], bw[ct][kf], acc[b][ct], 0, 0, 0);
    }

    // conv-half acc (waves 0-1) -> xr; gate half stays in registers
    if (wv < 2) {
        #pragma unroll
        for (int b = 0; b < 3; ++b)
            #pragma unroll
            for (int ct = 0; ct < 4; ++ct) {
                const int col = wv * 64 + ct * 16 + (lane & 15);
                #pragma unroll
                for (int i = 0; i < 4; ++i) {
                    int row = b * 16 + ((lane >> 4) << 2) + i;
                    if (row < 34) xr[row * XRS2 + col] = acc[b][ct][i];
                }
            }
    }
    __syncthreads();

    // Epilogue: conv+silu, 256 threads (channel = tid&127, token half = tid>>7)
    {
        int ch = tid & 127, s0 = (tid >> 7) * 16;
        float c0 = conv_w[ch * 3 + 0], c1 = conv_w[ch * 3 + 1], c2 = conv_w[ch * 3 + 2];
        float cb = conv_b[ch];
        float v0 = xr[(s0 + 0) * XRS2 + ch], v1 = xr[(s0 + 1) * XRS2 + ch];
        #pragma unroll
        for (int s = 0; s < 16; ++s) {
            float v2 = xr[(s0 + s + 2) * XRS2 + ch];
            float v = v0 * c0 + v1 * c1 + v2 * c2 + cb;
            v = v * sigmoidf_(v);
            xc[(size_t)(tstart + s0 + s) * D + ch] = v;
            short hh = f2bf(v);
            zsh[(s0 + s) * ZS + ch] = hh;
            zsl[(s0 + s) * ZS + ch] = f2bf(v - bf2f(hh));
            v0 = v1; v1 = v2;
        }
    }
    __syncthreads();

    // gate-half acc (waves 2-3) -> xr rows 2..33 (xr conv columns free now);
    if (wv >= 2) {
        #pragma unroll
        for (int b = 0; b < 3; ++b)
            #pragma unroll
            for (int ct = 0; ct < 4; ++ct) {
                const int col = (wv - 2) * 64 + ct * 16 + (lane & 15);
                #pragma unroll
                for (int i = 0; i < 4; ++i) {
                    int row = b * 16 + ((lane >> 4) << 2) + i;
                    if (row >= 2 && row < 34) xr[row * XRS2 + col] = acc[b][ct][i];
                }
            }
    }
    // Stage 2 MFMA: dbc = xc @ xp_w.T (M=32, N=48 padded, K=128), 3-term split.
    for (int tile = wv; tile < 6; tile += 4) {
        const int b = tile & 1, ct = tile >> 1;
        const int jcol = ct * 16 + (lane & 15);
        const int rbase = (b * 16 + (lane & 15)) * ZS + kb;
        bf16x8 ah[4], al[4], bh[4];
        #pragma unroll
        for (int kf = 0; kf < 4; ++kf) {
            ah[kf] = *(const bf16x8*)&zsh[rbase + kf * 32];
            al[kf] = *(const bf16x8*)&zsl[rbase + kf * 32];
            bh[kf] = *(const bf16x8*)&xph[jcol * 128 + kf * 32 + kb];
        }
        f32x4 a2 = (f32x4){0.f, 0.f, 0.f, 0.f};
        #pragma unroll
        for (int kf = 0; kf < 4; ++kf) {
            a2 = __builtin_amdgcn_mfma_f32_16x16x32_bf16(ah[kf], bh[kf], a2, 0, 0, 0);
            a2 = __builtin_amdgcn_mfma_f32_16x16x32_bf16(al[kf], bh[kf], a2, 0, 0, 0);
        }
        #pragma unroll
        for (int kf = 0; kf < 4; ++kf) {
            bh[kf] = *(const bf16x8*)&xpl[jcol * 128 + kf * 32 + kb];
            a2 = __builtin_amdgcn_mfma_f32_16x16x32_bf16(ah[kf], bh[kf], a2, 0, 0, 0);
        }
        #pragma unroll
        for (int i = 0; i < 4; ++i) {
            int t = b * 16 + ((lane >> 4) << 2) + i;
            dbc_l[t][jcol] = a2[i];
        }
    }
    __syncthreads();

    // Coalesced flush: res (32 x 512B), bc (4KB contig), dlt (1KB contig)
    for (int fi = tid; fi < 1024; fi += 256) {
        int r = fi >> 5, c4 = fi & 31;
        *(float4*)&res[(size_t)(tstart + r) * D + c4 * 4] =
            *(const float4*)&xr[(r + 2) * XRS2 + c4 * 4];
    }
    {
        int t = tid >> 3, q = tid & 7;
        *(float4*)&bc[(size_t)(tstart + t) * 32 + q * 4] = *(const float4*)&dbc_l[t][8 + q * 4];
    }
    if (tid < 64) {
        int t = tid >> 1, j4 = tid & 1;
        *(float4*)&dlt[(size_t)(tstart + t) * 8 + j4 * 4] = *(const float4*)&dbc_l[t][j4 * 4];
    }
}

// ---- LDS-free streaming selective scan, n-split: thread = (seg, d, nhalf) ----
// Lanes (2d, 2d+1) share a wave: nhalf merged via one shfl_xor. 8 states/thread.
// No __shared__, no barriers. Grid: 2048 blocks x 256 thr (1 segment/block).
// Pass 1: scan from x=0 -> F (8 states per thread), S = sum(dt) (nh==0 writes).
__global__ __launch_bounds__(256) void k_scan1(
    const float* __restrict__ xc, const float* __restrict__ bc,
    const float* __restrict__ dlt,
    const float* __restrict__ dp_w, const float* __restrict__ dp_b,
    const float* __restrict__ A2,
    float* __restrict__ Sbuf, float* __restrict__ Fbuf)
{
    const int tid = threadIdx.x;
    const int d = tid >> 1;          // 0..127
    const int nh = tid & 1;          // state half
    const int segid = blockIdx.x;    // 0..2047
    const size_t segbase = (size_t)segid * SEGLEN;

    float dpw[DR];
    #pragma unroll
    for (int r = 0; r < DR; ++r) dpw[r] = dp_w[d * DR + r];
    const float dpb = dp_b[d];
    float A2r[8];
    #pragma unroll
    for (int n = 0; n < 8; ++n) A2r[n] = A2[d * NSTATE + nh * 8 + n];
    float xs[8];
    #pragma unroll
    for (int n = 0; n < 8; ++n) xs[n] = 0.f;
    float S = 0.f;

    // prefetch step 0
    float4 dl0 = *(const float4*)&dlt[segbase * 8];
    float4 dl1 = *(const float4*)&dlt[segbase * 8 + 4];
    float4 B0 = *(const float4*)&bc[segbase * 32 + nh * 8 + 0];
    float4 B1 = *(const float4*)&bc[segbase * 32 + nh * 8 + 4];
    float uv = xc[segbase * D + d];

    for (int tl = 0; tl < SEGLEN; ++tl) {
        float4 cd0 = dl0, cd1 = dl1, cB0 = B0, cB1 = B1;
        float cu = uv;
        if (tl + 1 < SEGLEN) {
            const size_t nt = segbase + tl + 1;
            dl0 = *(const float4*)&dlt[nt * 8];
            dl1 = *(const float4*)&dlt[nt * 8 + 4];
            B0 = *(const float4*)&bc[nt * 32 + nh * 8 + 0];
            B1 = *(const float4*)&bc[nt * 32 + nh * 8 + 4];
            uv = xc[nt * D + d];
        }
        float v = dpb;
        v = fmaf(cd0.x, dpw[0], v); v = fmaf(cd0.y, dpw[1], v);
        v = fmaf(cd0.z, dpw[2], v); v = fmaf(cd0.w, dpw[3], v);
        v = fmaf(cd1.x, dpw[4], v); v = fmaf(cd1.y, dpw[5], v);
        v = fmaf(cd1.z, dpw[6], v); v = fmaf(cd1.w, dpw[7], v);
        float dt = softplusf_(v);
        float duv = dt * cu;
        S += dt;
        xs[0] = fmaf(exp2f(dt * A2r[0]), xs[0], duv * cB0.x);
        xs[1] = fmaf(exp2f(dt * A2r[1]), xs[1], duv * cB0.y);
        xs[2] = fmaf(exp2f(dt * A2r[2]), xs[2], duv * cB0.z);
        xs[3] = fmaf(exp2f(dt * A2r[3]), xs[3], duv * cB0.w);
        xs[4] = fmaf(exp2f(dt * A2r[4]), xs[4], duv * cB1.x);
        xs[5] = fmaf(exp2f(dt * A2r[5]), xs[5], duv * cB1.y);
        xs[6] = fmaf(exp2f(dt * A2r[6]), xs[6], duv * cB1.z);
        xs[7] = fmaf(exp2f(dt * A2r[7]), xs[7], duv * cB1.w);
    }
    const size_t o = ((size_t)segid * D + d) * NSTATE + nh * 8;
    *(float4*)&Fbuf[o + 0] = make_float4(xs[0], xs[1], xs[2], xs[3]);
    *(float4*)&Fbuf[o + 4] = make_float4(xs[4], xs[5], xs[6], xs[7]);
    if (nh == 0) Sbuf[(size_t)segid * D + d] = S;
}

// Pass 2: inline fix-up (P recomputed from S) -> x_init, re-scan;
// y = C.x (half-dots merged via shfl) + u*Dp, gated, -> resy.
__global__ __launch_bounds__(256) void k_scan2(
    const float* __restrict__ xc, const float* __restrict__ bc,
    const float* __restrict__ dlt,
    const float* __restrict__ dp_w, const float* __restrict__ dp_b,
    const float* __restrict__ A2, const float* __restrict__ Dp,
    const float* __restrict__ Sbuf, const float* __restrict__ Fbuf,
    float* __restrict__ resy)
{
    const int tid = threadIdx.x;
    const int d = tid >> 1;
    const int nh = tid & 1;
    const int segid = blockIdx.x;    // 0..2047
    const int seg = segid & (SEG - 1);
    const int seg0 = segid - seg;
    const size_t segbase = (size_t)segid * SEGLEN;

    float dpw[DR];
    #pragma unroll
    for (int r = 0; r < DR; ++r) dpw[r] = dp_w[d * DR + r];
    const float dpb = dp_b[d];
    float A2r[8];
    #pragma unroll
    for (int n = 0; n < 8; ++n) A2r[n] = A2[d * NSTATE + nh * 8 + n];
    const float Dpd = Dp[d];

    // inline fix-up: ascending combine x = P_s*x + F_s over predecessors
    float xs[8];
    #pragma unroll
    for (int n = 0; n < 8; ++n) xs[n] = 0.f;
    for (int s = 0; s < seg; ++s) {
        const int sid = seg0 + s;
        const float Sv = Sbuf[(size_t)sid * D + d];
        const size_t idx = ((size_t)sid * D + d) * NSTATE + nh * 8;
        float4 F0 = *(const float4*)&Fbuf[idx + 0];
        float4 F1 = *(const float4*)&Fbuf[idx + 4];
        xs[0] = fmaf(exp2f(A2r[0] * Sv), xs[0], F0.x);
        xs[1] = fmaf(exp2f(A2r[1] * Sv), xs[1], F0.y);
        xs[2] = fmaf(exp2f(A2r[2] * Sv), xs[2], F0.z);
        xs[3] = fmaf(exp2f(A2r[3] * Sv), xs[3], F0.w);
        xs[4] = fmaf(exp2f(A2r[4] * Sv), xs[4], F1.x);
        xs[5] = fmaf(exp2f(A2r[5] * Sv), xs[5], F1.y);
        xs[6] = fmaf(exp2f(A2r[6] * Sv), xs[6], F1.z);
        xs[7] = fmaf(exp2f(A2r[7] * Sv), xs[7], F1.w);
    }

    // prefetch step 0
    float4 dl0 = *(const float4*)&dlt[segbase * 8];
    float4 dl1 = *(const float4*)&dlt[segbase * 8 + 4];
    float4 B0 = *(const float4*)&bc[segbase * 32 + nh * 8 + 0];
    float4 B1 = *(const float4*)&bc[segbase * 32 + nh * 8 + 4];
    float4 C0 = *(const float4*)&bc[segbase * 32 + 16 + nh * 8 + 0];
    float4 C1 = *(const float4*)&bc[segbase * 32 + 16 + nh * 8 + 4];
    float uv = xc[segbase * D + d];
    float rg = resy[segbase * D + d];

    for (int tl = 0; tl < SEGLEN; ++tl) {
        float4 cd0 = dl0, cd1 = dl1;
        float4 cB0 = B0, cB1 = B1, cC0 = C0, cC1 = C1;
        float cu = uv, cg = rg;
        if (tl + 1 < SEGLEN) {
            const size_t nt = segbase + tl + 1;
            dl0 = *(const float4*)&dlt[nt * 8];
            dl1 = *(const float4*)&dlt[nt * 8 + 4];
            B0 = *(const float4*)&bc[nt * 32 + nh * 8 + 0];
            B1 = *(const float4*)&bc[nt * 32 + nh * 8 + 4];
            C0 = *(const float4*)&bc[nt * 32 + 16 + nh * 8 + 0];
            C1 = *(const float4*)&bc[nt * 32 + 16 + nh * 8 + 4];
            uv = xc[nt * D + d];
            rg = resy[nt * D + d];
        }
        float v = dpb;
        v = fmaf(cd0.x, dpw[0], v); v = fmaf(cd0.y, dpw[1], v);
        v = fmaf(cd0.z, dpw[2], v); v = fmaf(cd0.w, dpw[3], v);
        v = fmaf(cd1.x, dpw[4], v); v = fmaf(cd1.y, dpw[5], v);
        v = fmaf(cd1.z, dpw[6], v); v = fmaf(cd1.w, dpw[7], v);
        float dt = softplusf_(v);
        float duv = dt * cu;
        xs[0] = fmaf(exp2f(dt * A2r[0]), xs[0], duv * cB0.x);
        xs[1] = fmaf(exp2f(dt * A2r[1]), xs[1], duv * cB0.y);
        xs[2] = fmaf(exp2f(dt * A2r[2]), xs[2], duv * cB0.z);
        xs[3] = fmaf(exp2f(dt * A2r[3]), xs[3], duv * cB0.w);
        xs[4] = fmaf(exp2f(dt * A2r[4]), xs[4], duv * cB1.x);
        xs[5] = fmaf(exp2f(dt * A2r[5]), xs[5], duv * cB1.y);
        xs[6] = fmaf(exp2f(dt * A2r[6]), xs[6], duv * cB1.z);
        xs[7] = fmaf(exp2f(dt * A2r[7]), xs[7], duv * cB1.w);
        float y = xs[0] * cC0.x;
        y = fmaf(xs[1], cC0.y, y);
        y = fmaf(xs[2], cC0.z, y);
        y = fmaf(xs[3], cC0.w, y);
        y = fmaf(xs[4], cC1.x, y);
        y = fmaf(xs[5], cC1.y, y);
        y = fmaf(xs[6], cC1.z, y);
        y = fmaf(xs[7], cC1.w, y);
        y += __shfl_xor(y, 1);       // merge the two state-halves (lane pair)
        if (nh == 0) {
            y = fmaf(cu, Dpd, y);
            resy[(segbase + tl) * D + d] = y * (cg * sigmoidf_(cg));
        }
    }
}

// out_proj + residual via 3-term split-bf16 MFMA: h[t] += y[t] @ out_w.T
__global__ __launch_bounds__(256) void k_outproj(
    const float* __restrict__ y, const short* __restrict__ wh, const short* __restrict__ wl,
    float* __restrict__ h)
{
    __shared__ __align__(16) short ysh[32 * ZS];
    __shared__ __align__(16) short ysl[32 * ZS];
    const int tid = threadIdx.x;
    const int wv = tid >> 6, lane = tid & 63;
    const size_t tb = (size_t)blockIdx.x * 32;

    #pragma unroll
    for (int i = 0; i < 4; ++i) {
        int idx = tid + i * 256;
        int row = idx >> 5, c4 = idx & 31;
        float4 v = *(const float4*)&y[(tb + row) * D + c4 * 4];
        short h0 = f2bf(v.x), h1 = f2bf(v.y), h2 = f2bf(v.z), h3 = f2bf(v.w);
        *(short4*)&ysh[row * ZS + c4 * 4] = make_short4(h0, h1, h2, h3);
        *(short4*)&ysl[row * ZS + c4 * 4] = make_short4(
            f2bf(v.x - bf2f(h0)), f2bf(v.y - bf2f(h1)),
            f2bf(v.z - bf2f(h2)), f2bf(v.w - bf2f(h3)));
    }

    const int colb = wv * 32 + (lane & 15);
    const int kb = (lane >> 4) * 8;
    bf16x8 bw[2][4];
    #pragma unroll
    for (int ct = 0; ct < 2; ++ct)
        #pragma unroll
        for (int kf = 0; kf < 4; ++kf)
            bw[ct][kf] = *(const bf16x8*)&wh[(colb + ct * 16) * 128 + kf * 32 + kb];
    __syncthreads();

    f32x4 acc[2][2];
    #pragma unroll
    for (int b = 0; b < 2; ++b)
        #pragma unroll
        for (int ct = 0; ct < 2; ++ct)
            acc[b][ct] = (f32x4){0.f, 0.f, 0.f, 0.f};

    #pragma unroll
    for (int b = 0; b < 2; ++b) {
        bf16x8 ah[4], al[4];
        const int rbase = (b * 16 + (lane & 15)) * ZS + kb;
        #pragma unroll
        for (int kf = 0; kf < 4; ++kf) {
            ah[kf] = *(const bf16x8*)&ysh[rbase + kf * 32];
            al[kf] = *(const bf16x8*)&ysl[rbase + kf * 32];
        }
        #pragma unroll
        for (int ct = 0; ct < 2; ++ct)
            #pragma unroll
            for (int kf = 0; kf < 4; ++kf) {
                acc[b][ct] = __builtin_amdgcn_mfma_f32_16x16x32_bf16(ah[kf], bw[ct][kf], acc[b][ct], 0, 0, 0);
                acc[b][ct] = __builtin_amdgcn_mfma_f32_16x16x32_bf16(al[kf], bw[ct][kf], acc[b][ct], 0, 0, 0);
            }
    }
    #pragma unroll
    for (int ct = 0; ct < 2; ++ct)
        #pragma unroll
        for (int kf = 0; kf < 4; ++kf)
            bw[ct][kf] = *(const bf16x8*)&wl[(colb + ct * 16) * 128 + kf * 32 + kb];
    #pragma unroll
    for (int b = 0; b < 2; ++b) {
        bf16x8 ah[4];
        const int rbase = (b * 16 + (lane & 15)) * ZS + kb;
        #pragma unroll
        for (int kf = 0; kf < 4; ++kf)
            ah[kf] = *(const bf16x8*)&ysh[rbase + kf * 32];
        #pragma unroll
        for (int ct = 0; ct < 2; ++ct)
            #pragma unroll
            for (int kf = 0; kf < 4; ++kf)
                acc[b][ct] = __builtin_amdgcn_mfma_f32_16x16x32_bf16(ah[kf], bw[ct][kf], acc[b][ct], 0, 0, 0);
    }

    #pragma unroll
    for (int b = 0; b < 2; ++b)
        #pragma unroll
        for (int ct = 0; ct < 2; ++ct) {
            const int col = wv * 32 + ct * 16 + (lane & 15);
            #pragma unroll
            for (int i = 0; i < 4; ++i) {
                int row = b * 16 + ((lane >> 4) << 2) + i;
                size_t o = (tb + row) * D + col;
                h[o] += acc[b][ct][i];
            }
        }
}

// out[t] = h[t] . outp_w + outp_b  (one wave per token)
__global__ __launch_bounds__(256) void k_final(
    const float* __restrict__ h, const float* __restrict__ outp_w,
    const float* __restrict__ outp_b, float* __restrict__ out)
{
    const int tid = threadIdx.x;
    const int lane = tid & 63;
    const size_t tok = (size_t)blockIdx.x * 4 + (tid >> 6);
    float a = h[tok * D + lane] * outp_w[lane] + h[tok * D + lane + 64] * outp_w[lane + 64];
    #pragma unroll
    for (int m = 1; m < 64; m <<= 1) a += __shfl_xor(a, m);
    if (lane == 0) out[tok] = a + outp_b[0];
}

extern "C" void kernel_launch(void* const* d_in, const int* in_sizes, int n_in,
                              void* d_out, int out_size, void* d_ws, size_t ws_size,
                              hipStream_t stream)
{
    const float* x      = (const float*)d_in[0];
    const float* inp_w  = (const float*)d_in[1];
    const float* inp_b  = (const float*)d_in[2];
    const float* outp_w = (const float*)d_in[3];
    const float* outp_b = (const float*)d_in[4];
    const float* ln_g   = (const float*)d_in[5];
    const float* ln_b   = (const float*)d_in[6];
    const float* in_w   = (const float*)d_in[7];
    const float* conv_w = (const float*)d_in[8];
    const float* conv_b = (const float*)d_in[9];
    const float* xp_w   = (const float*)d_in[10];
    const float* dp_w   = (const float*)d_in[11];
    const float* dp_b   = (const float*)d_in[12];
    const float* A_log  = (const float*)d_in[13];
    const float* Dp     = (const float*)d_in[14];
    const float* out_w  = (const float*)d_in[15];

    float* ws = (float*)d_ws;
    size_t off = 0;
    float* h      = ws + off; off += (size_t)NTOK * D;
    float* xc     = ws + off; off += (size_t)NTOK * D;
    float* resy   = ws + off; off += (size_t)NTOK * D;
    float* bc     = ws + off; off += (size_t)NTOK * 32;
    float* dlt    = ws + off; off += (size_t)NTOK * 8;
    float* Fbuf   = ws + off; off += 128 * SEG * 2048;   // 2048 segs x 128 d x 16 n
    float* Sbuf   = ws + off; off += 128 * SEG * 128;    // 2048 segs x 128 d
    short* in_wBh = (short*)(ws + off); off += 4 * 256 * 128 / 2;
    short* in_wBl = (short*)(ws + off); off += 4 * 256 * 128 / 2;
    short* out_wBh= (short*)(ws + off); off += 4 * 128 * 128 / 2;
    short* out_wBl= (short*)(ws + off); off += 4 * 128 * 128 / 2;
    short* xp_wBh = (short*)(ws + off); off += 4 * 48 * 128 / 2;
    short* xp_wBl = (short*)(ws + off); off += 4 * 48 * 128 / 2;
    float* A2     = ws + off; off += 4 * 128 * 16;
    if (ws_size < off * sizeof(float)) return;  // workspace too small -> fail visibly

    // prep
    k_prepw<<<(4 * 256 * 128 + 255) / 256, 256, 0, stream>>>(in_w, in_wBh, in_wBl, 4 * 256 * 128);
    k_prepw<<<(4 * 128 * 128 + 255) / 256, 256, 0, stream>>>(out_w, out_wBh, out_wBl, 4 * 128 * 128);
    k_prepw_xp<<<(4 * 48 * 128 + 255) / 256, 256, 0, stream>>>(xp_w, xp_wBh, xp_wBl);
    k_a2<<<(4 * 128 * 16 + 255) / 256, 256, 0, stream>>>(A_log, A2, 4 * 128 * 16);
    k_init_h<<<NTOK * D / 256, 256, 0, stream>>>(x, inp_w, inp_b, h);

    for (int l = 0; l < 4; ++l) {
        k_ln_inproj_conv<<<NTOK / 32, 256, 0, stream>>>(
            h, ln_g + l * 128, ln_b + l * 128,
            in_wBh + l * 256 * 128, in_wBl + l * 256 * 128,
            xp_wBh + l * 48 * 128, xp_wBl + l * 48 * 128,
            conv_w + l * 128 * 3, conv_b + l * 128, xc, resy, bc, dlt);
        k_scan1<<<2048, 256, 0, stream>>>(xc, bc, dlt, dp_w + l * 128 * 8, dp_b + l * 128,
                                          A2 + l * 128 * 16, Sbuf, Fbuf);
        k_scan2<<<2048, 256, 0, stream>>>(xc, bc, dlt, dp_w + l * 128 * 8, dp_b + l * 128,
                                          A2 + l * 128 * 16, Dp + l * 128, Sbuf, Fbuf, resy);
        k_outproj<<<NTOK / 32, 256, 0, stream>>>(resy, out_wBh + l * 128 * 128,
                                                 out_wBl + l * 128 * 128, h);
    }
    k_final<<<NTOK / 4, 256, 0, stream>>>(h, outp_w, outp_b, (float*)d_out);
}

// Round 20
// 1515.959 us; speedup vs baseline: 1.0814x; 1.0324x over previous
//
#include <hip/hip_runtime.h>
#include <math.h>

#define D 128
#define NSTATE 16
#define DR 8
#define T_SEQ 1024
#define NTOK 131072  // 128 sequences * 1024 tokens
#define SEG 8        // segments per sequence (parallel scan)
#define SEGLEN 128   // T_SEQ / SEG
#define CH 16        // chunk (timesteps staged in LDS at once)
#define ZS 136       // bf16 elems per z row (128 + 8 pad -> 272B stride)
#define XRS2 132     // f32 elems per xr row (128 + 4 pad)

typedef __attribute__((ext_vector_type(8))) short bf16x8;
typedef __attribute__((ext_vector_type(4))) float f32x4;

#define LOG2E 1.44269504088896340736f
#define LN2   0.69314718055994530942f

// fast sigmoid: 1/(1+2^(-x*log2e)) via v_exp + v_rcp (~1 ulp)
__device__ __forceinline__ float sigmoidf_(float x) {
    return __builtin_amdgcn_rcpf(1.0f + exp2f(-x * LOG2E));
}
// fast softplus: ln2 * log2(1 + 2^(x*log2e)) via v_exp + v_log
__device__ __forceinline__ float softplusf_(float x) {
    float t = LN2 * __builtin_amdgcn_logf(1.0f + exp2f(x * LOG2E));
    return (x > 20.0f) ? x : t;
}
__device__ __forceinline__ short f2bf(float f) {   // RNE float->bf16
    union { float f; unsigned u; } v; v.f = f;
    unsigned r = v.u + 0x7FFFu + ((v.u >> 16) & 1u);
    return (short)(r >> 16);
}
__device__ __forceinline__ float bf2f(short s) {
    union { unsigned u; float f; } v; v.u = ((unsigned)(unsigned short)s) << 16;
    return v.f;
}

// ---------------- prep kernels ----------------

// f32 -> bf16 hi/lo split, elementwise (layout preserved)
__global__ void k_prepw(const float* __restrict__ src, short* __restrict__ hi,
                        short* __restrict__ lo, int n) {
    int i = blockIdx.x * 256 + threadIdx.x;
    if (i < n) {
        float f = src[i];
        short hh = f2bf(f);
        hi[i] = hh;
        lo[i] = f2bf(f - bf2f(hh));
    }
}

// xp_w (L,40,128) -> padded (L,48,128) bf16 hi/lo, rows 40..47 zero
__global__ void k_prepw_xp(const float* __restrict__ src, short* __restrict__ hi,
                           short* __restrict__ lo) {
    int i = blockIdx.x * 256 + threadIdx.x;     // over 4*48*128
    if (i >= 4 * 48 * 128) return;
    int l = i / (48 * 128);
    int rem = i - l * 48 * 128;
    int j = rem >> 7, k = rem & 127;
    float f = (j < 40) ? src[(l * 40 + j) * 128 + k] : 0.f;
    short hh = f2bf(f);
    hi[i] = hh;
    lo[i] = f2bf(f - bf2f(hh));
}

// A2 = -exp(A_log) * log2(e)
__global__ void k_a2(const float* __restrict__ A_log, float* __restrict__ A2, int total) {
    int idx = blockIdx.x * blockDim.x + threadIdx.x;
    if (idx < total) A2[idx] = -__expf(A_log[idx]) * LOG2E;
}

// h[tok][d] = x[tok] * inp_w[d] + inp_b[d]
__global__ void k_init_h(const float* __restrict__ x, const float* __restrict__ inp_w,
                         const float* __restrict__ inp_b, float* __restrict__ h) {
    int idx = blockIdx.x * blockDim.x + threadIdx.x;
    int tok = idx >> 7;
    int d = idx & 127;
    h[idx] = x[tok] * inp_w[d] + inp_b[d];
}

// ---------------- per-layer kernels ----------------
// Fused LN + in_proj (3-term split-bf16 MFMA) + causal conv(k=3) + SiLU
// + x_proj (second MFMA stage) -> xc, res, bc, dlt. Coalesced flush via LDS.
__global__ __launch_bounds__(256) void k_ln_inproj_conv(
    const float* __restrict__ h, const float* __restrict__ ln_g, const float* __restrict__ ln_b,
    const short* __restrict__ wh, const short* __restrict__ wl,   // in_proj (256,128) hi/lo
    const short* __restrict__ xph, const short* __restrict__ xpl, // x_proj padded (48,128) hi/lo
    const float* __restrict__ conv_w, const float* __restrict__ conv_b,
    float* __restrict__ xc, float* __restrict__ res,
    float* __restrict__ bc, float* __restrict__ dlt)
{
    __shared__ __align__(16) short zsh[48 * ZS];
    __shared__ __align__(16) short zsl[48 * ZS];
    __shared__ __align__(16) float xr[34 * XRS2];
    __shared__ __align__(16) float dbc_l[32][52];   // stage-2 out (40 used, 52 stride)
    const int tid = threadIdx.x;
    const int wv = tid >> 6, lane = tid & 63;
    const int tstart = blockIdx.x * 32;
    const int tin = tstart & (T_SEQ - 1);

    // Phase A: LayerNorm rows 0..33 -> bf16 hi/lo
    for (int r = wv; r < 34; r += 4) {
        int tr = tin + r - 2;
        if (tr < 0) {
            zsh[r * ZS + lane] = 0; zsh[r * ZS + lane + 64] = 0;
            zsl[r * ZS + lane] = 0; zsl[r * ZS + lane + 64] = 0;
            continue;
        }
        size_t row = (size_t)(tstart + r - 2) * D;
        float a = h[row + lane];
        float b = h[row + lane + 64];
        float s = a + b, ss = a * a + b * b;
        #pragma unroll
        for (int m = 1; m < 64; m <<= 1) { s += __shfl_xor(s, m); ss += __shfl_xor(ss, m); }
        float mu = s * (1.0f / 128.0f);
        float var = ss * (1.0f / 128.0f) - mu * mu;
        float rstd = rsqrtf(var + 1e-5f);
        float z0 = (a - mu) * rstd * ln_g[lane]      + ln_b[lane];
        float z1 = (b - mu) * rstd * ln_g[lane + 64] + ln_b[lane + 64];
        short h0 = f2bf(z0), h1 = f2bf(z1);
        zsh[r * ZS + lane]      = h0;
        zsh[r * ZS + lane + 64] = h1;
        zsl[r * ZS + lane]      = f2bf(z0 - bf2f(h0));
        zsl[r * ZS + lane + 64] = f2bf(z1 - bf2f(h1));
    }
    for (int i = tid; i < 14 * 128; i += 256) {
        int r = 34 + (i >> 7), c = i & 127;
        zsh[r * ZS + c] = 0;
        zsl[r * ZS + c] = 0;
    }

    // B panel (hi) -> registers
    const int colb = wv * 64 + (lane & 15);
    const int kb = (lane >> 4) * 8;
    bf16x8 bw[4][4];
    #pragma unroll
    for (int ct = 0; ct < 4; ++ct)
        #pragma unroll
        for (int kf = 0; kf < 4; ++kf)
            bw[ct][kf] = *(const bf16x8*)&wh[(colb + ct * 16) * 128 + kf * 32 + kb];
    __syncthreads();

    f32x4 acc[3][4];
    #pragma unroll
    for (int b = 0; b < 3; ++b)
        #pragma unroll
        for (int ct = 0; ct < 4; ++ct)
            acc[b][ct] = (f32x4){0.f, 0.f, 0.f, 0.f};

    // Pass 1: (a_hi + a_lo) * b_hi
    #pragma unroll
    for (int b = 0; b < 3; ++b) {
        bf16x8 ah[4], al[4];
        const int rbase = (b * 16 + (lane & 15)) * ZS + kb;
        #pragma unroll
        for (int kf = 0; kf < 4; ++kf) {
            ah[kf] = *(const bf16x8*)&zsh[rbase + kf * 32];
            al[kf] = *(const bf16x8*)&zsl[rbase + kf * 32];
        }
        #pragma unroll
        for (int ct = 0; ct < 4; ++ct)
            #pragma unroll
            for (int kf = 0; kf < 4; ++kf) {
                acc[b][ct] = __builtin_amdgcn_mfma_f32_16x16x32_bf16(ah[kf], bw[ct][kf], acc[b][ct], 0, 0, 0);
                acc[b][ct] = __builtin_amdgcn_mfma_f32_16x16x32_bf16(al[kf], bw[ct][kf], acc[b][ct], 0, 0, 0);
            }
    }
    // Pass 2: a_hi * b_lo
    #pragma unroll
    for (int ct = 0; ct < 4; ++ct)
        #pragma unroll
        for (int kf = 0; kf < 4; ++kf)
            bw[ct][kf] = *(const bf16x8*)&wl[(colb + ct * 16) * 128 + kf * 32 + kb];
    #pragma unroll
    for (int b = 0; b < 3; ++b) {
        bf16x8 ah[4];
        const int rbase = (b * 16 + (lane & 15)) * ZS + kb;
        #pragma unroll
        for (int kf = 0; kf < 4; ++kf)
            ah[kf] = *(const bf16x8*)&zsh[rbase + kf * 32];
        #pragma unroll
        for (int ct = 0; ct < 4; ++ct)
            #pragma unroll
            for (int kf = 0; kf < 4; ++kf)
                acc[b][ct] = __builtin_amdgcn_mfma_f32_16x16x32_bf16(ah[kf], bw[ct][kf], acc[b][ct], 0, 0, 0);
    }

    // conv-half acc (waves 0-1) -> xr; gate half stays in registers
    if (wv < 2) {
        #pragma unroll
        for (int b = 0; b < 3; ++b)
            #pragma unroll
            for (int ct = 0; ct < 4; ++ct) {
                const int col = wv * 64 + ct * 16 + (lane & 15);
                #pragma unroll
                for (int i = 0; i < 4; ++i) {
                    int row = b * 16 + ((lane >> 4) << 2) + i;
                    if (row < 34) xr[row * XRS2 + col] = acc[b][ct][i];
                }
            }
    }
    __syncthreads();

    // Epilogue: conv+silu, 256 threads (channel = tid&127, token half = tid>>7)
    {
        int ch = tid & 127, s0 = (tid >> 7) * 16;
        float c0 = conv_w[ch * 3 + 0], c1 = conv_w[ch * 3 + 1], c2 = conv_w[ch * 3 + 2];
        float cb = conv_b[ch];
        float v0 = xr[(s0 + 0) * XRS2 + ch], v1 = xr[(s0 + 1) * XRS2 + ch];
        #pragma unroll
        for (int s = 0; s < 16; ++s) {
            float v2 = xr[(s0 + s + 2) * XRS2 + ch];
            float v = v0 * c0 + v1 * c1 + v2 * c2 + cb;
            v = v * sigmoidf_(v);
            xc[(size_t)(tstart + s0 + s) * D + ch] = v;
            short hh = f2bf(v);
            zsh[(s0 + s) * ZS + ch] = hh;
            zsl[(s0 + s) * ZS + ch] = f2bf(v - bf2f(hh));
            v0 = v1; v1 = v2;
        }
    }
    __syncthreads();

    // gate-half acc (waves 2-3) -> xr rows 2..33 (xr conv columns free now);
    if (wv >= 2) {
        #pragma unroll
        for (int b = 0; b < 3; ++b)
            #pragma unroll
            for (int ct = 0; ct < 4; ++ct) {
                const int col = (wv - 2) * 64 + ct * 16 + (lane & 15);
                #pragma unroll
                for (int i = 0; i < 4; ++i) {
                    int row = b * 16 + ((lane >> 4) << 2) + i;
                    if (row >= 2 && row < 34) xr[row * XRS2 + col] = acc[b][ct][i];
                }
            }
    }
    // Stage 2 MFMA: dbc = xc @ xp_w.T (M=32, N=48 padded, K=128), 3-term split.
    for (int tile = wv; tile < 6; tile += 4) {
        const int b = tile & 1, ct = tile >> 1;
        const int jcol = ct * 16 + (lane & 15);
        const int rbase = (b * 16 + (lane & 15)) * ZS + kb;
        bf16x8 ah[4], al[4], bh[4];
        #pragma unroll
        for (int kf = 0; kf < 4; ++kf) {
            ah[kf] = *(const bf16x8*)&zsh[rbase + kf * 32];
            al[kf] = *(const bf16x8*)&zsl[rbase + kf * 32];
            bh[kf] = *(const bf16x8*)&xph[jcol * 128 + kf * 32 + kb];
        }
        f32x4 a2 = (f32x4){0.f, 0.f, 0.f, 0.f};
        #pragma unroll
        for (int kf = 0; kf < 4; ++kf) {
            a2 = __builtin_amdgcn_mfma_f32_16x16x32_bf16(ah[kf], bh[kf], a2, 0, 0, 0);
            a2 = __builtin_amdgcn_mfma_f32_16x16x32_bf16(al[kf], bh[kf], a2, 0, 0, 0);
        }
        #pragma unroll
        for (int kf = 0; kf < 4; ++kf) {
            bh[kf] = *(const bf16x8*)&xpl[jcol * 128 + kf * 32 + kb];
            a2 = __builtin_amdgcn_mfma_f32_16x16x32_bf16(ah[kf], bh[kf], a2, 0, 0, 0);
        }
        #pragma unroll
        for (int i = 0; i < 4; ++i) {
            int t = b * 16 + ((lane >> 4) << 2) + i;
            dbc_l[t][jcol] = a2[i];
        }
    }
    __syncthreads();

    // Coalesced flush: res (32 x 512B), bc (4KB contig), dlt (1KB contig)
    for (int fi = tid; fi < 1024; fi += 256) {
        int r = fi >> 5, c4 = fi & 31;
        *(float4*)&res[(size_t)(tstart + r) * D + c4 * 4] =
            *(const float4*)&xr[(r + 2) * XRS2 + c4 * 4];
    }
    {
        int t = tid >> 3, q = tid & 7;
        *(float4*)&bc[(size_t)(tstart + t) * 32 + q * 4] = *(const float4*)&dbc_l[t][8 + q * 4];
    }
    if (tid < 64) {
        int t = tid >> 1, j4 = tid & 1;
        *(float4*)&dlt[(size_t)(tstart + t) * 8 + j4 * 4] = *(const float4*)&dbc_l[t][j4 * 4];
    }
}

// ---- chunk-parallel selective scan (round-13 proven) ----
// Pass 1: per-segment scan from x=0 -> F, P. Grid 2048 x 256. B-half staging only.
__global__ __launch_bounds__(256) void k_scan1(
    const float* __restrict__ xc, const float* __restrict__ bc,
    const float* __restrict__ dlt,
    const float* __restrict__ dp_w, const float* __restrict__ dp_b,
    const float* __restrict__ A2,
    float* __restrict__ Pbuf, float* __restrict__ Fbuf)
{
    __shared__ float u_l[CH][64];
    __shared__ float du_l[CH][64];
    __shared__ float bc_l[CH][16];
    __shared__ float dlt_l[CH][8];
    __shared__ float dl_l[CH][64];
    __shared__ float dpw_s[64][9];
    __shared__ float dpb_s[64];

    const int tid = threadIdx.x;
    const int bt = blockIdx.x >> 4;
    const int seg = (blockIdx.x >> 1) & 7;
    const int d0 = (blockIdx.x & 1) * 64;
    const int dd = tid >> 2, q = tid & 3;
    const int d = d0 + dd;

    #pragma unroll
    for (int i = 0; i < 2; ++i) {
        int idx = tid + i * 256;
        dpw_s[idx >> 3][idx & 7] = dp_w[(d0 + (idx >> 3)) * 8 + (idx & 7)];
    }
    if (tid < 64) dpb_s[tid] = dp_b[d0 + tid];
    float A2q[4];
    #pragma unroll
    for (int jn = 0; jn < 4; ++jn) A2q[jn] = A2[d * NSTATE + q * 4 + jn];
    float x0 = 0.f, x1 = 0.f, x2 = 0.f, x3 = 0.f, S = 0.f;

    const size_t segbase = (size_t)bt * T_SEQ + (size_t)seg * SEGLEN;
    float4 su, sbc, sdl;
    su = *(const float4*)&xc[(segbase + (tid >> 4)) * D + d0 + (tid & 15) * 4];
    if (tid < 64)  sbc = *(const float4*)&bc[(segbase + (tid >> 2)) * 32 + (tid & 3) * 4];
    if (tid < 32)  sdl = *(const float4*)&dlt[(segbase + (tid >> 1)) * 8 + (tid & 1) * 4];

    for (int c = 0; c < SEGLEN / CH; ++c) {
        *(float4*)&u_l[tid >> 4][(tid & 15) * 4] = su;
        if (tid < 64)  *(float4*)&bc_l[tid >> 2][(tid & 3) * 4] = sbc;
        if (tid < 32)  *(float4*)&dlt_l[tid >> 1][(tid & 1) * 4] = sdl;
        __syncthreads();
        if (c + 1 < SEGLEN / CH) {
            const size_t nb = segbase + (size_t)(c + 1) * CH;
            su = *(const float4*)&xc[(nb + (tid >> 4)) * D + d0 + (tid & 15) * 4];
            if (tid < 64)  sbc = *(const float4*)&bc[(nb + (tid >> 2)) * 32 + (tid & 3) * 4];
            if (tid < 32)  sdl = *(const float4*)&dlt[(nb + (tid >> 1)) * 8 + (tid & 1) * 4];
        }
        {
            int col = tid & 63;
            #pragma unroll
            for (int i = 0; i < 4; ++i) {
                int row = (tid >> 6) + 4 * i;
                float v = dpb_s[col];
                #pragma unroll
                for (int r = 0; r < DR; ++r) v = fmaf(dlt_l[row][r], dpw_s[col][r], v);
                float dt = softplusf_(v);
                dl_l[row][col] = dt;
                du_l[row][col] = dt * u_l[row][col];
            }
        }
        __syncthreads();
        #pragma unroll
        for (int tl = 0; tl < CH; ++tl) {
            float dt = dl_l[tl][dd];
            float duv = du_l[tl][dd];
            S += dt;
            float4 Bq = *(const float4*)&bc_l[tl][q * 4];
            x0 = fmaf(exp2f(dt * A2q[0]), x0, duv * Bq.x);
            x1 = fmaf(exp2f(dt * A2q[1]), x1, duv * Bq.y);
            x2 = fmaf(exp2f(dt * A2q[2]), x2, duv * Bq.z);
            x3 = fmaf(exp2f(dt * A2q[3]), x3, duv * Bq.w);
        }
        __syncthreads();
    }
    const size_t o = ((size_t)(bt * SEG + seg) * D + d) * NSTATE + q * 4;
    *(float4*)&Fbuf[o] = make_float4(x0, x1, x2, x3);
    *(float4*)&Pbuf[o] = make_float4(exp2f(A2q[0] * S), exp2f(A2q[1] * S),
                                     exp2f(A2q[2] * S), exp2f(A2q[3] * S));
}

// Pass 2: inline fix-up then re-scan; y = C.x + u*Dp, gated, stored over res.
__global__ __launch_bounds__(256) void k_scan2(
    const float* __restrict__ xc, const float* __restrict__ bc,
    const float* __restrict__ dlt,
    const float* __restrict__ dp_w, const float* __restrict__ dp_b,
    const float* __restrict__ A2, const float* __restrict__ Dp,
    const float* __restrict__ Pbuf, const float* __restrict__ Fbuf,
    float* __restrict__ resy)
{
    __shared__ float u_l[CH][64];
    __shared__ float r_l[CH][64];
    __shared__ float bc_l[CH][32];
    __shared__ float dlt_l[CH][8];
    __shared__ float dl_l[CH][64];
    __shared__ float dpw_s[64][9];
    __shared__ float dpb_s[64];

    const int tid = threadIdx.x;
    const int bt = blockIdx.x >> 4;
    const int seg = (blockIdx.x >> 1) & 7;
    const int d0 = (blockIdx.x & 1) * 64;
    const int dd = tid >> 2, q = tid & 3;
    const int d = d0 + dd;

    #pragma unroll
    for (int i = 0; i < 2; ++i) {
        int idx = tid + i * 256;
        dpw_s[idx >> 3][idx & 7] = dp_w[(d0 + (idx >> 3)) * 8 + (idx & 7)];
    }
    if (tid < 64) dpb_s[tid] = dp_b[d0 + tid];
    float A2q[4];
    #pragma unroll
    for (int jn = 0; jn < 4; ++jn) A2q[jn] = A2[d * NSTATE + q * 4 + jn];
    const float Dpd = Dp[d];

    // inline fix-up: x_init = serial combine over segments 0..seg-1
    float x0 = 0.f, x1 = 0.f, x2 = 0.f, x3 = 0.f;
    for (int s = 0; s < seg; ++s) {
        const size_t idx = ((size_t)(bt * SEG + s) * D + d) * NSTATE + q * 4;
        float4 P = *(const float4*)&Pbuf[idx];
        float4 F = *(const float4*)&Fbuf[idx];
        x0 = fmaf(P.x, x0, F.x);
        x1 = fmaf(P.y, x1, F.y);
        x2 = fmaf(P.z, x2, F.z);
        x3 = fmaf(P.w, x3, F.w);
    }

    const size_t segbase = (size_t)bt * T_SEQ + (size_t)seg * SEGLEN;
    float4 su, sr, sbc, sdl;
    su = *(const float4*)&xc[(segbase + (tid >> 4)) * D + d0 + (tid & 15) * 4];
    sr = *(const float4*)&resy[(segbase + (tid >> 4)) * D + d0 + (tid & 15) * 4];
    if (tid < 128) sbc = *(const float4*)&bc[(segbase + (tid >> 3)) * 32 + (tid & 7) * 4];
    if (tid < 32)  sdl = *(const float4*)&dlt[(segbase + (tid >> 1)) * 8 + (tid & 1) * 4];

    for (int c = 0; c < SEGLEN / CH; ++c) {
        const size_t tb = segbase + (size_t)c * CH;
        *(float4*)&u_l[tid >> 4][(tid & 15) * 4] = su;
        *(float4*)&r_l[tid >> 4][(tid & 15) * 4] = sr;
        if (tid < 128) *(float4*)&bc_l[tid >> 3][(tid & 7) * 4] = sbc;
        if (tid < 32)  *(float4*)&dlt_l[tid >> 1][(tid & 1) * 4] = sdl;
        __syncthreads();
        if (c + 1 < SEGLEN / CH) {
            const size_t nb = tb + CH;
            su = *(const float4*)&xc[(nb + (tid >> 4)) * D + d0 + (tid & 15) * 4];
            sr = *(const float4*)&resy[(nb + (tid >> 4)) * D + d0 + (tid & 15) * 4];
            if (tid < 128) sbc = *(const float4*)&bc[(nb + (tid >> 3)) * 32 + (tid & 7) * 4];
            if (tid < 32)  sdl = *(const float4*)&dlt[(nb + (tid >> 1)) * 8 + (tid & 1) * 4];
        }
        {
            int col = tid & 63;
            #pragma unroll
            for (int i = 0; i < 4; ++i) {
                int row = (tid >> 6) + 4 * i;
                float v = dpb_s[col];
                #pragma unroll
                for (int r = 0; r < DR; ++r) v = fmaf(dlt_l[row][r], dpw_s[col][r], v);
                dl_l[row][col] = softplusf_(v);
            }
        }
        __syncthreads();
        float pacc[CH];
        #pragma unroll
        for (int tl = 0; tl < CH; ++tl) {
            float dt = dl_l[tl][dd];
            float uv = u_l[tl][dd];
            float duv = dt * uv;
            float4 Bq = *(const float4*)&bc_l[tl][q * 4];
            float4 Cq = *(const float4*)&bc_l[tl][16 + q * 4];
            x0 = fmaf(exp2f(dt * A2q[0]), x0, duv * Bq.x);
            x1 = fmaf(exp2f(dt * A2q[1]), x1, duv * Bq.y);
            x2 = fmaf(exp2f(dt * A2q[2]), x2, duv * Bq.z);
            x3 = fmaf(exp2f(dt * A2q[3]), x3, duv * Bq.w);
            float p = x0 * Cq.x;
            p = fmaf(x1, Cq.y, p);
            p = fmaf(x2, Cq.z, p);
            p = fmaf(x3, Cq.w, p);
            p += __shfl_xor(p, 1);
            p += __shfl_xor(p, 2);
            pacc[tl] = fmaf(uv, Dpd, p);
        }
        if (q == 0) {
            #pragma unroll
            for (int tl = 0; tl < CH; ++tl) {
                float g = r_l[tl][dd];
                resy[(tb + tl) * D + d] = pacc[tl] * (g * sigmoidf_(g));
            }
        }
        __syncthreads();
    }
}

// out_proj + residual via 3-term split-bf16 MFMA: h[t] += y[t] @ out_w.T
__global__ __launch_bounds__(256) void k_outproj(
    const float* __restrict__ y, const short* __restrict__ wh, const short* __restrict__ wl,
    float* __restrict__ h)
{
    __shared__ __align__(16) short ysh[32 * ZS];
    __shared__ __align__(16) short ysl[32 * ZS];
    const int tid = threadIdx.x;
    const int wv = tid >> 6, lane = tid & 63;
    const size_t tb = (size_t)blockIdx.x * 32;

    #pragma unroll
    for (int i = 0; i < 4; ++i) {
        int idx = tid + i * 256;
        int row = idx >> 5, c4 = idx & 31;
        float4 v = *(const float4*)&y[(tb + row) * D + c4 * 4];
        short h0 = f2bf(v.x), h1 = f2bf(v.y), h2 = f2bf(v.z), h3 = f2bf(v.w);
        *(short4*)&ysh[row * ZS + c4 * 4] = make_short4(h0, h1, h2, h3);
        *(short4*)&ysl[row * ZS + c4 * 4] = make_short4(
            f2bf(v.x - bf2f(h0)), f2bf(v.y - bf2f(h1)),
            f2bf(v.z - bf2f(h2)), f2bf(v.w - bf2f(h3)));
    }

    const int colb = wv * 32 + (lane & 15);
    const int kb = (lane >> 4) * 8;
    bf16x8 bw[2][4];
    #pragma unroll
    for (int ct = 0; ct < 2; ++ct)
        #pragma unroll
        for (int kf = 0; kf < 4; ++kf)
            bw[ct][kf] = *(const bf16x8*)&wh[(colb + ct * 16) * 128 + kf * 32 + kb];
    __syncthreads();

    f32x4 acc[2][2];
    #pragma unroll
    for (int b = 0; b < 2; ++b)
        #pragma unroll
        for (int ct = 0; ct < 2; ++ct)
            acc[b][ct] = (f32x4){0.f, 0.f, 0.f, 0.f};

    #pragma unroll
    for (int b = 0; b < 2; ++b) {
        bf16x8 ah[4], al[4];
        const int rbase = (b * 16 + (lane & 15)) * ZS + kb;
        #pragma unroll
        for (int kf = 0; kf < 4; ++kf) {
            ah[kf] = *(const bf16x8*)&ysh[rbase + kf * 32];
            al[kf] = *(const bf16x8*)&ysl[rbase + kf * 32];
        }
        #pragma unroll
        for (int ct = 0; ct < 2; ++ct)
            #pragma unroll
            for (int kf = 0; kf < 4; ++kf) {
                acc[b][ct] = __builtin_amdgcn_mfma_f32_16x16x32_bf16(ah[kf], bw[ct][kf], acc[b][ct], 0, 0, 0);
                acc[b][ct] = __builtin_amdgcn_mfma_f32_16x16x32_bf16(al[kf], bw[ct][kf], acc[b][ct], 0, 0, 0);
            }
    }
    #pragma unroll
    for (int ct = 0; ct < 2; ++ct)
        #pragma unroll
        for (int kf = 0; kf < 4; ++kf)
            bw[ct][kf] = *(const bf16x8*)&wl[(colb + ct * 16) * 128 + kf * 32 + kb];
    #pragma unroll
    for (int b = 0; b < 2; ++b) {
        bf16x8 ah[4];
        const int rbase = (b * 16 + (lane & 15)) * ZS + kb;
        #pragma unroll
        for (int kf = 0; kf < 4; ++kf)
            ah[kf] = *(const bf16x8*)&ysh[rbase + kf * 32];
        #pragma unroll
        for (int ct = 0; ct < 2; ++ct)
            #pragma unroll
            for (int kf = 0; kf < 4; ++kf)
                acc[b][ct] = __builtin_amdgcn_mfma_f32_16x16x32_bf16(ah[kf], bw[ct][kf], acc[b][ct], 0, 0, 0);
    }

    #pragma unroll
    for (int b = 0; b < 2; ++b)
        #pragma unroll
        for (int ct = 0; ct < 2; ++ct) {
            const int col = wv * 32 + ct * 16 + (lane & 15);
            #pragma unroll
            for (int i = 0; i < 4; ++i) {
                int row = b * 16 + ((lane >> 4) << 2) + i;
                size_t o = (tb + row) * D + col;
                h[o] += acc[b][ct][i];
            }
        }
}

// out[t] = h[t] . outp_w + outp_b  (one wave per token)
__global__ __launch_bounds__(256) void k_final(
    const float* __restrict__ h, const float* __restrict__ outp_w,
    const float* __restrict__ outp_b, float* __restrict__ out)
{
    const int tid = threadIdx.x;
    const int lane = tid & 63;
    const size_t tok = (size_t)blockIdx.x * 4 + (tid >> 6);
    float a = h[tok * D + lane] * outp_w[lane] + h[tok * D + lane + 64] * outp_w[lane + 64];
    #pragma unroll
    for (int m = 1; m < 64; m <<= 1) a += __shfl_xor(a, m);
    if (lane == 0) out[tok] = a + outp_b[0];
}

extern "C" void kernel_launch(void* const* d_in, const int* in_sizes, int n_in,
                              void* d_out, int out_size, void* d_ws, size_t ws_size,
                              hipStream_t stream)
{
    const float* x      = (const float*)d_in[0];
    const float* inp_w  = (const float*)d_in[1];
    const float* inp_b  = (const float*)d_in[2];
    const float* outp_w = (const float*)d_in[3];
    const float* outp_b = (const float*)d_in[4];
    const float* ln_g   = (const float*)d_in[5];
    const float* ln_b   = (const float*)d_in[6];
    const float* in_w   = (const float*)d_in[7];
    const float* conv_w = (const float*)d_in[8];
    const float* conv_b = (const float*)d_in[9];
    const float* xp_w   = (const float*)d_in[10];
    const float* dp_w   = (const float*)d_in[11];
    const float* dp_b   = (const float*)d_in[12];
    const float* A_log  = (const float*)d_in[13];
    const float* Dp     = (const float*)d_in[14];
    const float* out_w  = (const float*)d_in[15];

    float* ws = (float*)d_ws;
    size_t off = 0;
    float* h      = ws + off; off += (size_t)NTOK * D;
    float* xc     = ws + off; off += (size_t)NTOK * D;
    float* resy   = ws + off; off += (size_t)NTOK * D;
    float* bc     = ws + off; off += (size_t)NTOK * 32;
    float* dlt    = ws + off; off += (size_t)NTOK * 8;
    float* Pbuf   = ws + off; off += 128 * SEG * 2048;
    float* Fbuf   = ws + off; off += 128 * SEG * 2048;
    short* in_wBh = (short*)(ws + off); off += 4 * 256 * 128 / 2;
    short* in_wBl = (short*)(ws + off); off += 4 * 256 * 128 / 2;
    short* out_wBh= (short*)(ws + off); off += 4 * 128 * 128 / 2;
    short* out_wBl= (short*)(ws + off); off += 4 * 128 * 128 / 2;
    short* xp_wBh = (short*)(ws + off); off += 4 * 48 * 128 / 2;
    short* xp_wBl = (short*)(ws + off); off += 4 * 48 * 128 / 2;
    float* A2     = ws + off; off += 4 * 128 * 16;
    if (ws_size < off * sizeof(float)) return;  // workspace too small -> fail visibly

    // prep
    k_prepw<<<(4 * 256 * 128 + 255) / 256, 256, 0, stream>>>(in_w, in_wBh, in_wBl, 4 * 256 * 128);
    k_prepw<<<(4 * 128 * 128 + 255) / 256, 256, 0, stream>>>(out_w, out_wBh, out_wBl, 4 * 128 * 128);
    k_prepw_xp<<<(4 * 48 * 128 + 255) / 256, 256, 0, stream>>>(xp_w, xp_wBh, xp_wBl);
    k_a2<<<(4 * 128 * 16 + 255) / 256, 256, 0, stream>>>(A_log, A2, 4 * 128 * 16);
    k_init_h<<<NTOK * D / 256, 256, 0, stream>>>(x, inp_w, inp_b, h);

    for (int l = 0; l < 4; ++l) {
        k_ln_inproj_conv<<<NTOK / 32, 256, 0, stream>>>(
            h, ln_g + l * 128, ln_b + l * 128,
            in_wBh + l * 256 * 128, in_wBl + l * 256 * 128,
            xp_wBh + l * 48 * 128, xp_wBl + l * 48 * 128,
            conv_w + l * 128 * 3, conv_b + l * 128, xc, resy, bc, dlt);
        k_scan1<<<2048, 256, 0, stream>>>(xc, bc, dlt, dp_w + l * 128 * 8, dp_b + l * 128,
                                          A2 + l * 128 * 16, Pbuf, Fbuf);
        k_scan2<<<2048, 256, 0, stream>>>(xc, bc, dlt, dp_w + l * 128 * 8, dp_b + l * 128,
                                          A2 + l * 128 * 16, Dp + l * 128, Pbuf, Fbuf, resy);
        k_outproj<<<NTOK / 32, 256, 0, stream>>>(resy, out_wBh + l * 128 * 128,
                                                 out_wBl + l * 128 * 128, h);
    }
    k_final<<<NTOK / 4, 256, 0, stream>>>(h, outp_w, outp_b, (float*)d_out);
}